// Round 6
// baseline (1814.180 us; speedup 1.0000x reference)
//
#include <hip/hip_runtime.h>
#include <cstdint>
#include <cstddef>
#include <math.h>

#define BB    4
#define NN    12800
#define FF    16
#define DIN   23
#define NCLS  8
#define DDIM  128
#define HID   256
#define NBINS 20
#define BS    640
#define KNB   16
#define EE    (NN*KNB)   /* 204800 edges per batch */
#define BN    (BB*NN)    /* 51200 points total */

__device__ __forceinline__ float eluf(float x){ return x > 0.f ? x : expm1f(x); }
__device__ __forceinline__ float seluf(float x){
  const float a = 1.6732632423543772f, s = 1.0507009873554805f;
  return x > 0.f ? s*x : s*a*expm1f(x);
}
__device__ __forceinline__ float sigf(float x){ return 1.f/(1.f+expf(-x)); }

// ---------------- h0 = [one_hot(X[:,:,0],8), X[:,:,1:]] -> (BN,23) ----------
__global__ void k_h0(const float* __restrict__ X, float* __restrict__ h0){
  int id = blockIdx.x*256 + threadIdx.x;
  if (id >= BN*DIN) return;
  int p = id / DIN, f = id % DIN;
  const float* xr = X + (size_t)p*FF;
  float v;
  if (f < NCLS){
    int cls = (int)xr[0];
    v = (f == cls) ? 1.f : 0.f;
  } else {
    v = xr[f - NCLS + 1];
  }
  h0[id] = v;
}

// ------ pe = elu(h0@We1+be1)@We2+be2 -> (BN,128), fp64 internally -----------
// pe feeds the discrete LSH argmax and top-k comparisons; computing it in
// fp64 and rounding once makes our pe the correctly-rounded true value,
// minimizing discrete-choice flips vs the numpy reference.
__global__ void k_pe(const float* __restrict__ h0,
                     const float* __restrict__ We1, const float* __restrict__ be1,
                     const float* __restrict__ We2, const float* __restrict__ be2,
                     float* __restrict__ pe){
  __shared__ double hid[2][128];
  int t = threadIdx.x;
  int lp = t >> 7, j = t & 127;
  size_t p = (size_t)blockIdx.x*2 + lp;
  const float* hr = h0 + p*DIN;
  double acc = (double)be1[j];
  #pragma unroll
  for (int k=0;k<DIN;++k) acc += (double)hr[k]*(double)We1[k*DDIM + j];
  hid[lp][j] = acc > 0.0 ? acc : expm1(acc);
  __syncthreads();
  double acc2 = (double)be2[j];
  #pragma unroll 8
  for (int k=0;k<DDIM;++k) acc2 += hid[lp][k]*(double)We2[k*DDIM + j];
  pe[p*DDIM + j] = (float)acc2;
}

// ---------------- LSH bin id: argmax over [pe@R10, -pe@R10] -----------------
// 4 lanes per point; fp64 accumulation (f32 products are exact in f64),
// rounded to f32 before the argmax compare to mirror numpy semantics.
__global__ void k_binid(const float* __restrict__ pe, const float* __restrict__ R,
                        int* __restrict__ bid){
  int tid = blockIdx.x*256 + threadIdx.x;   // grid sized so tid < 4*BN
  int p = tid >> 2, part = tid & 3;
  const float* pr = pe + (size_t)p*DDIM + part*32;
  double m[10];
  #pragma unroll
  for (int j=0;j<10;++j) m[j] = 0.0;
  #pragma unroll 4
  for (int k=0;k<32;++k){
    double v = (double)pr[k];
    const float* rr = R + (size_t)(part*32 + k)*100;  // R (128,100) row-major, cols 0..9
    #pragma unroll
    for (int j=0;j<10;++j) m[j] += v*(double)rr[j];
  }
  #pragma unroll
  for (int j=0;j<10;++j){
    m[j] += __shfl_xor(m[j], 1);
    m[j] += __shfl_xor(m[j], 2);
  }
  if (part == 0){
    float mf[10];
    #pragma unroll
    for (int j=0;j<10;++j) mf[j] = (float)m[j];
    float bv = -1e30f; int bi = 0;
    #pragma unroll
    for (int j=0;j<20;++j){
      float v = (j<10) ? mf[j] : -mf[j-10];
      if (v > bv){ bv = v; bi = j; }   // strict > : first-max = jnp.argmax
    }
    bid[p] = bi;
  }
}

// ---------------- stable counting sort -> order (permutation) ---------------
// one block per (batch, bin); replicates stable argsort of integer keys.
__global__ void k_place(const int* __restrict__ binid, int* __restrict__ order){
  int b = blockIdx.x / NBINS, mybin = blockIdx.x % NBINS;
  const int* bid = binid + (size_t)b*NN;
  int t = threadIdx.x;
  __shared__ int wsum[4];
  __shared__ int wtot[4];
  __shared__ int sOff;
  // offset = #points with smaller bin id
  int c = 0;
  for (int i = t; i < NN; i += 256) c += (bid[i] < mybin) ? 1 : 0;
  #pragma unroll
  for (int o=32;o;o>>=1) c += __shfl_xor(c, o);
  if ((t & 63) == 0) wsum[t >> 6] = c;
  __syncthreads();
  if (t == 0) sOff = wsum[0]+wsum[1]+wsum[2]+wsum[3];
  __syncthreads();
  int base = sOff;
  int lane = t & 63, w = t >> 6;
  for (int ch = 0; ch < NN; ch += 256){
    int i = ch + t;
    bool flag = (i < NN) && (bid[i] == mybin);
    unsigned long long bal = __ballot(flag);
    int pre = __popcll(bal & ((1ull << lane) - 1ull));
    if (lane == 0) wtot[w] = __popcll(bal);
    __syncthreads();
    int woff = 0;
    #pragma unroll
    for (int ww=0; ww<4; ++ww) if (ww < w) woff += wtot[ww];
    if (flag) order[(size_t)b*NN + base + woff + pre] = i;
    base += wtot[0]+wtot[1]+wtot[2]+wtot[3];
    __syncthreads();
  }
}

// ---------------- per-bin dense sim + top-16 --------------------------------
// block = (batch, bin, row-tile of 64). 64x64 S tiles; fp64 dot accumulation
// (f32 tiles in LDS), rounded to f32 -> sigmoid f32 -> selection.
#define TP 68
__global__ void __launch_bounds__(256)
k_topk(const float* __restrict__ pe, const int* __restrict__ order,
       float* __restrict__ valk, int* __restrict__ idxk){
  __shared__ float rowT[64][TP];   // [k_local][row]
  __shared__ float colT[64][TP];   // [k_local][col]
  __shared__ float S[64][69];      // S[row][col]; reused for merge values
  __shared__ unsigned short midx[64][48];
  __shared__ int ordRow[64];
  __shared__ int ordCol[64];
  int blk = blockIdx.x;
  int b   = blk / (NBINS*10);
  int rem = blk % (NBINS*10);
  int bin = rem / 10, rt = rem % 10;
  int r0 = rt*64;
  int t = threadIdx.x;
  const float* peb = pe + (size_t)b*NN*DDIM;
  const int* ob = order + (size_t)b*NN + (size_t)bin*BS;
  if (t < 64) ordRow[t] = ob[r0 + t];

  float tv[16]; int ti[16];
  #pragma unroll
  for (int j=0;j<16;++j){ tv[j] = -1e30f; ti[j] = 1<<20; }
  float wv = -1e30f; int wi = 1<<20; int wpos = 0;

  int tm = t & 15, tn = t >> 4;       // compute mapping: rows 4tm.., cols 4tn..
  int rsel = t & 63, qsel = t >> 6;   // selection mapping: row rsel, col-quarter qsel

  for (int ct = 0; ct < 10; ++ct){
    __syncthreads();                   // prev selection done; safe to reuse LDS
    if (t < 64) ordCol[t] = ob[ct*64 + t];
    double acc[4][4];
    #pragma unroll
    for (int i=0;i<4;++i){
      #pragma unroll
      for (int j=0;j<4;++j) acc[i][j] = 0.0;
    }
    #pragma unroll
    for (int kh = 0; kh < 2; ++kh){
      __syncthreads();
      for (int l=t; l<4096; l+=256){
        int rr = l >> 6, kk = l & 63;
        rowT[kk][rr] = peb[(size_t)ordRow[rr]*DDIM + kh*64 + kk];
      }
      for (int l=t; l<4096; l+=256){
        int cc = l >> 6, kk = l & 63;
        colT[kk][cc] = peb[(size_t)ordCol[cc]*DDIM + kh*64 + kk];
      }
      __syncthreads();
      #pragma unroll 4
      for (int kk=0; kk<64; ++kk){
        float4 a = *(const float4*)&rowT[kk][4*tm];
        float4 w = *(const float4*)&colT[kk][4*tn];
        double ad[4], wd[4];
        ad[0]=(double)a.x; ad[1]=(double)a.y; ad[2]=(double)a.z; ad[3]=(double)a.w;
        wd[0]=(double)w.x; wd[1]=(double)w.y; wd[2]=(double)w.z; wd[3]=(double)w.w;
        #pragma unroll
        for (int i=0;i<4;++i){
          #pragma unroll
          for (int j=0;j<4;++j) acc[i][j] += ad[i]*wd[j];
        }
      }
    }
    #pragma unroll
    for (int i=0;i<4;++i){
      #pragma unroll
      for (int j=0;j<4;++j)
        S[4*tm+i][4*tn+j] = sigf((float)acc[i][j]);
    }
    __syncthreads();
    // selection: each thread streams 16 candidates of its row-quarter
    #pragma unroll
    for (int j=0;j<16;++j){
      float v = S[rsel][qsel*16 + j];
      int gc = ct*64 + qsel*16 + j;
      bool better = (v > wv) || (v == wv && gc < wi);
      if (better){
        #pragma unroll
        for (int u=0;u<16;++u){ if (u == wpos){ tv[u] = v; ti[u] = gc; } }
        wv = tv[0]; wi = ti[0]; wpos = 0;
        #pragma unroll
        for (int u=1;u<16;++u){
          bool worse = (tv[u] < wv) || (tv[u] == wv && ti[u] > wi);
          if (worse){ wv = tv[u]; wi = ti[u]; wpos = u; }
        }
      }
    }
  }
  // merge the 4 per-quarter lists per row
  __syncthreads();
  if (qsel > 0){
    #pragma unroll
    for (int j=0;j<16;++j){
      S[rsel][(qsel-1)*16 + j] = tv[j];
      midx[rsel][(qsel-1)*16 + j] = (unsigned short)ti[j];
    }
  }
  __syncthreads();
  if (qsel == 0){
    for (int j=0;j<48;++j){
      float v = S[rsel][j]; int gc = (int)midx[rsel][j];
      bool better = (v > wv) || (v == wv && gc < wi);
      if (better){
        #pragma unroll
        for (int u=0;u<16;++u){ if (u == wpos){ tv[u] = v; ti[u] = gc; } }
        wv = tv[0]; wi = ti[0]; wpos = 0;
        #pragma unroll
        for (int u=1;u<16;++u){
          bool worse = (tv[u] < wv) || (tv[u] == wv && ti[u] > wi);
          if (worse){ wv = tv[u]; wi = ti[u]; wpos = u; }
        }
      }
    }
    size_t base = (((size_t)(b*NBINS + bin))*BS + r0 + rsel)*KNB;
    #pragma unroll
    for (int j=0;j<16;++j){ valk[base + j] = tv[j]; idxk[base + j] = ti[j]; }
  }
}

// -------- per-node edge-FFN partials: spart = bd1 + h0@Wd1[0:23],
//          dpart = h0@Wd1[23:46]  (each (BN,128)) -----------------------------
__global__ void k_epart(const float* __restrict__ h0,
                        const float* __restrict__ Wd1, const float* __restrict__ bd1,
                        float* __restrict__ spart, float* __restrict__ dpart){
  int t = threadIdx.x;
  int lp = t >> 7, j = t & 127;
  size_t p = (size_t)blockIdx.x*2 + lp;
  const float* hr = h0 + p*DIN;
  float sa = bd1[j];
  float da = 0.f;
  #pragma unroll
  for (int k=0;k<DIN;++k){
    float x = hr[k];
    sa += x*Wd1[k*128 + j];
    da += x*Wd1[(DIN+k)*128 + j];
  }
  spart[p*128 + j] = sa;
  dpart[p*128 + j] = da;
}

// ---------------- edge FFN (decomposed): one wave per edge ------------------
__global__ void k_edges(const float* __restrict__ spart, const float* __restrict__ dpart,
                        const int* __restrict__ order,
                        const float* __restrict__ valk, const int* __restrict__ idxk,
                        const float* __restrict__ Wd1, const float* __restrict__ Wd2,
                        const float* __restrict__ bd2,
                        float* __restrict__ wgt, int* __restrict__ dste){
  int lane = threadIdx.x & 63;
  size_t e = (size_t)blockIdx.x*4 + (threadIdx.x >> 6);
  int b  = (int)(e / EE);
  int eb = (int)(e % EE);
  int bin = eb / (BS*KNB);
  int rem = eb % (BS*KNB);
  int i  = rem / KNB;
  int kk = rem % KNB;
  const int* ob = order + (size_t)b*NN + (size_t)bin*BS;
  int src = ob[i];
  size_t tkb = ((size_t)(b*NBINS + bin)*BS + i)*KNB + kk;
  int ip = idxk[tkb];
  int dst = ob[ip];
  float dv = valk[tkb];
  size_t gs = ((size_t)b*NN + src)*128;
  size_t gd = ((size_t)b*NN + dst)*128;
  float a1 = spart[gs + lane]      + dpart[gd + lane]      + dv*Wd1[46*128 + lane];
  float a2 = spart[gs + 64 + lane] + dpart[gd + 64 + lane] + dv*Wd1[46*128 + 64 + lane];
  float ptl = eluf(a1)*Wd2[lane] + eluf(a2)*Wd2[lane + 64];
  #pragma unroll
  for (int o=32;o;o>>=1) ptl += __shfl_xor(ptl, o);
  if (lane == 0){
    wgt[e]  = sigf(ptl + bd2[0]);
    dste[e] = dst;
  }
}

// ---------------- degree -> norm (per node) ---------------------------------
__global__ void k_deg(const float* __restrict__ wgt, const int* __restrict__ order,
                      float* __restrict__ nrm){
  int id = blockIdx.x*256 + threadIdx.x;
  if (id >= BN) return;
  int b = id / NN;
  int p = id % NN;
  const float* w = wgt + (size_t)b*EE + (size_t)p*KNB;
  float s = 0.f;
  #pragma unroll
  for (int k=0;k<KNB;++k) s += fabsf(w[k]);
  int node = order[id];
  nrm[(size_t)b*NN + node] = 1.f/sqrtf(s + 1e-6f);
}

// ---------------- encoder: selu(h0@Wenc+benc), 8 points / block -------------
__global__ void k_enc(const float* __restrict__ h0, const float* __restrict__ Wenc,
                      const float* __restrict__ benc, float* __restrict__ xe){
  __shared__ float hs[8][DIN+1];
  size_t p0 = (size_t)blockIdx.x*8;
  int t = threadIdx.x;
  if (t < 8*DIN){
    int pp = t / DIN, ff = t - pp*DIN;
    hs[pp][ff] = h0[(p0+pp)*DIN + ff];
  }
  float wreg[DIN];
  #pragma unroll
  for (int k=0;k<DIN;++k) wreg[k] = Wenc[k*HID + t];
  float bb = benc[t];
  __syncthreads();
  #pragma unroll
  for (int pp=0;pp<8;++pp){
    float acc = bb;
    #pragma unroll
    for (int k=0;k<DIN;++k) acc += hs[pp][k]*wreg[k];
    xe[(p0+pp)*HID + t] = seluf(acc);
  }
}

// ------- 128x128-tile GEMM: (BN x 256) @ (256 x 256), 8x8 per thread --------
// MODE 0: C=A@W ; 1: C=(A@W)*rs[row] ; 2: sigmoid(A@W+b) ; 3: selu(A@W+b)
template<int MODE>
__global__ void __launch_bounds__(256)
k_gemm128(const float* __restrict__ A, const float* __restrict__ W,
          const float* __restrict__ bias, const float* __restrict__ rs,
          float* __restrict__ C){
  __shared__ float As[16][132];   // [k][m] transposed A tile
  __shared__ float Ws[16][132];   // [k][n]
  int t = threadIdx.x;
  int m0 = blockIdx.x*128, n0 = blockIdx.y*128;
  int tx = t & 15, ty = t >> 4;
  float acc[8][8];
  #pragma unroll
  for (int i=0;i<8;++i){
    #pragma unroll
    for (int j=0;j<8;++j) acc[i][j] = 0.f;
  }
  for (int kt=0; kt<16; ++kt){
    int k0 = kt*16;
    __syncthreads();
    #pragma unroll
    for (int l=0;l<8;++l){
      int idx = t + l*256;
      int m = idx >> 4, kk = idx & 15;
      As[kk][m] = A[((size_t)(m0+m))*HID + k0 + kk];
    }
    #pragma unroll
    for (int l=0;l<8;++l){
      int idx = t + l*256;
      int kk = idx >> 7, nn = idx & 127;
      Ws[kk][nn] = W[((size_t)(k0+kk))*HID + n0 + nn];
    }
    __syncthreads();
    #pragma unroll
    for (int kk=0;kk<16;++kk){
      float4 a0 = *(const float4*)&As[kk][4*ty];
      float4 a1 = *(const float4*)&As[kk][64 + 4*ty];
      float4 w0 = *(const float4*)&Ws[kk][4*tx];
      float4 w1 = *(const float4*)&Ws[kk][64 + 4*tx];
      float av[8], wv[8];
      av[0]=a0.x; av[1]=a0.y; av[2]=a0.z; av[3]=a0.w;
      av[4]=a1.x; av[5]=a1.y; av[6]=a1.z; av[7]=a1.w;
      wv[0]=w0.x; wv[1]=w0.y; wv[2]=w0.z; wv[3]=w0.w;
      wv[4]=w1.x; wv[5]=w1.y; wv[6]=w1.z; wv[7]=w1.w;
      #pragma unroll
      for (int i=0;i<8;++i){
        #pragma unroll
        for (int j=0;j<8;++j) acc[i][j] += av[i]*wv[j];
      }
    }
  }
  float b0[8];
  if (MODE == 2 || MODE == 3){
    #pragma unroll
    for (int j=0;j<8;++j) b0[j] = bias[n0 + (j<4 ? 4*tx+j : 60+4*tx+j)];
  }
  #pragma unroll
  for (int i=0;i<8;++i){
    int row = m0 + (i<4 ? 4*ty+i : 60+4*ty+i);
    float sc = (MODE == 1) ? rs[row] : 1.f;
    float v[8];
    #pragma unroll
    for (int j=0;j<8;++j){
      float x = acc[i][j];
      if (MODE == 2 || MODE == 3) x += b0[j];
      if (MODE == 1) x *= sc;
      if (MODE == 2) x = sigf(x);
      if (MODE == 3) x = seluf(x);
      v[j] = x;
    }
    float4 r0; r0.x=v[0]; r0.y=v[1]; r0.z=v[2]; r0.w=v[3];
    float4 r1; r1.x=v[4]; r1.y=v[5]; r1.z=v[6]; r1.w=v[7];
    *(float4*)&C[(size_t)row*HID + n0 + 4*tx]      = r0;
    *(float4*)&C[(size_t)row*HID + n0 + 64 + 4*tx] = r1;
  }
}

// ---------------- GHConv combine --------------------------------------------
__global__ void k_combine(const float* __restrict__ fh, const float* __restrict__ xh,
                          const float* __restrict__ gate, const float* __restrict__ wgt,
                          const int* __restrict__ dste, const int* __restrict__ order,
                          const float* __restrict__ nrm, float* __restrict__ xg){
  __shared__ float ew[KNB];
  __shared__ int   ed[KNB];
  int blk = blockIdx.x;
  int b = blk / NN, p = blk % NN;
  int t = threadIdx.x;
  if (t < KNB){
    size_t e = (size_t)b*EE + (size_t)p*KNB + t;
    ew[t] = wgt[e];
    ed[t] = dste[e];
  }
  __syncthreads();
  int src = order[(size_t)b*NN + p];
  float nr = nrm[(size_t)b*NN + src];
  size_t base = (size_t)b*NN*HID;
  float acc = 0.f;
  #pragma unroll
  for (int k=0;k<KNB;++k) acc += ew[k]*fh[base + (size_t)ed[k]*HID + t];
  acc *= nr;
  size_t o = base + (size_t)src*HID + t;
  float g = gate[o];
  xg[o] = seluf(g*acc + (1.f - g)*xh[o]);
}

// ---------------- output head: one wave per point ---------------------------
__global__ void k_head(const float* __restrict__ xd, const float* __restrict__ Wout,
                       const float* __restrict__ bout, float* __restrict__ out){
  int lane = threadIdx.x & 63;
  size_t p = (size_t)blockIdx.x*4 + (threadIdx.x >> 6);
  float4 x = *(const float4*)&xd[p*HID + lane*4];
  float a0 = 0.f, a1 = 0.f, a2 = 0.f;
  const float* wr = Wout + lane*4*3;
  a0 += x.x*wr[0]; a1 += x.x*wr[1]; a2 += x.x*wr[2];
  a0 += x.y*wr[3]; a1 += x.y*wr[4]; a2 += x.y*wr[5];
  a0 += x.z*wr[6]; a1 += x.z*wr[7]; a2 += x.z*wr[8];
  a0 += x.w*wr[9]; a1 += x.w*wr[10]; a2 += x.w*wr[11];
  #pragma unroll
  for (int o=32;o;o>>=1){
    a0 += __shfl_xor(a0, o);
    a1 += __shfl_xor(a1, o);
    a2 += __shfl_xor(a2, o);
  }
  if (lane == 0){
    out[p*3 + 0] = a0 + bout[0];
    out[p*3 + 1] = a1 + bout[1];
    out[p*3 + 2] = a2 + bout[2];
  }
}

// ---------------------------------------------------------------------------
extern "C" void kernel_launch(void* const* d_in, const int* in_sizes, int n_in,
                              void* d_out, int out_size, void* d_ws, size_t ws_size,
                              hipStream_t stream){
  (void)in_sizes; (void)n_in; (void)out_size; (void)ws_size;
  const float* X    = (const float*)d_in[0];
  const float* We1  = (const float*)d_in[1];
  const float* be1  = (const float*)d_in[2];
  const float* We2  = (const float*)d_in[3];
  const float* be2  = (const float*)d_in[4];
  const float* Wd1  = (const float*)d_in[5];
  const float* bd1  = (const float*)d_in[6];
  const float* Wd2  = (const float*)d_in[7];
  const float* bd2  = (const float*)d_in[8];
  const float* R    = (const float*)d_in[9];
  const float* Wenc = (const float*)d_in[10];
  const float* benc = (const float*)d_in[11];
  const float* Wt   = (const float*)d_in[12];
  const float* bt   = (const float*)d_in[13];
  const float* Wh   = (const float*)d_in[14];
  const float* theta= (const float*)d_in[15];
  const float* Wdec = (const float*)d_in[16];
  const float* bdec = (const float*)d_in[17];
  const float* Wout = (const float*)d_in[18];
  const float* bout = (const float*)d_in[19];
  float* out = (float*)d_out;

  char* ws = (char*)d_ws; size_t off = 0;
  auto alloc = [&](size_t bytes)->void*{
    void* p = ws + off; off = (off + bytes + 255) & ~(size_t)255; return p;
  };
  float* h0   = (float*)alloc((size_t)BN*DIN*4);
  float* pe   = (float*)alloc((size_t)BN*DDIM*4);
  int*   bid  = (int*)  alloc((size_t)BN*4);
  int*   order= (int*)  alloc((size_t)BN*4);
  float* valk = (float*)alloc((size_t)BB*NBINS*BS*KNB*4);
  int*   idxk = (int*)  alloc((size_t)BB*NBINS*BS*KNB*4);
  float* wgt  = (float*)alloc((size_t)BB*EE*4);
  int*   dste = (int*)  alloc((size_t)BB*EE*4);
  float* nrm  = (float*)alloc((size_t)BN*4);
  float* xe   = (float*)alloc((size_t)BN*HID*4);
  float* fh   = (float*)alloc((size_t)BN*HID*4);
  float* xh   = (float*)alloc((size_t)BN*HID*4);
  float* gate = (float*)alloc((size_t)BN*HID*4);
  // aliases (stream-ordered; aliased buffer dead before alias written):
  float* spart = pe;   // (BN,128) == pe exactly; pe dead after k_topk
  float* dpart = xe;   // (BN,128) fits in xe; xe written by k_enc AFTER k_edges
  float* xg    = xe;   // combine output; xe dead after the 3 GHConv gemms
  float* xd    = fh;   // decoder output; fh dead after k_combine

  k_h0   <<<(BN*DIN + 255)/256, 256, 0, stream>>>(X, h0);
  k_pe   <<<BN/2, 256, 0, stream>>>(h0, We1, be1, We2, be2, pe);
  k_binid<<<BN*4/256, 256, 0, stream>>>(pe, R, bid);
  k_place<<<BB*NBINS, 256, 0, stream>>>(bid, order);
  k_topk <<<BB*NBINS*10, 256, 0, stream>>>(pe, order, valk, idxk);
  k_epart<<<BN/2, 256, 0, stream>>>(h0, Wd1, bd1, spart, dpart);
  k_edges<<<BB*EE/4, 256, 0, stream>>>(spart, dpart, order, valk, idxk, Wd1, Wd2, bd2, wgt, dste);
  k_deg  <<<(BN + 255)/256, 256, 0, stream>>>(wgt, order, nrm);
  k_enc  <<<BN/8, 256, 0, stream>>>(h0, Wenc, benc, xe);
  dim3 gg(BN/128, HID/128);
  k_gemm128<0><<<gg, 256, 0, stream>>>(xe, Wh,    nullptr, nullptr, xh);
  k_gemm128<1><<<gg, 256, 0, stream>>>(xe, theta, nullptr, nrm,     fh);
  k_gemm128<2><<<gg, 256, 0, stream>>>(xe, Wt,    bt,      nullptr, gate);
  k_combine<<<BN, 256, 0, stream>>>(fh, xh, gate, wgt, dste, order, nrm, xg);
  k_gemm128<3><<<gg, 256, 0, stream>>>(xg, Wdec,  bdec,    nullptr, xd);
  k_head <<<BN/4, 256, 0, stream>>>(xd, Wout, bout, out);
}

// Round 8
// 1745.962 us; speedup vs baseline: 1.0391x; 1.0391x over previous
//
#include <hip/hip_runtime.h>
#include <cstdint>
#include <cstddef>
#include <math.h>

#define BB    4
#define NN    12800
#define FF    16
#define DIN   23
#define NCLS  8
#define DDIM  128
#define HID   256
#define NBINS 20
#define BS    640
#define KNB   16
#define EE    (NN*KNB)   /* 204800 edges per batch */
#define BN    (BB*NN)    /* 51200 points total */

__device__ __forceinline__ float eluf(float x){ return x > 0.f ? x : expm1f(x); }
__device__ __forceinline__ float seluf(float x){
  const float a = 1.6732632423543772f, s = 1.0507009873554805f;
  return x > 0.f ? s*x : s*a*expm1f(x);
}
__device__ __forceinline__ float sigf(float x){ return 1.f/(1.f+expf(-x)); }

// ---------------- h0 = [one_hot(X[:,:,0],8), X[:,:,1:]] -> (BN,23) ----------
__global__ void k_h0(const float* __restrict__ X, float* __restrict__ h0){
  int id = blockIdx.x*256 + threadIdx.x;
  if (id >= BN*DIN) return;
  int p = id / DIN, f = id % DIN;
  const float* xr = X + (size_t)p*FF;
  float v;
  if (f < NCLS){
    int cls = (int)xr[0];
    v = (f == cls) ? 1.f : 0.f;
  } else {
    v = xr[f - NCLS + 1];
  }
  h0[id] = v;
}

// ------ pe = elu(h0@We1+be1)@We2+be2 -> (BN,128), fp64 internally -----------
// pe feeds the discrete LSH argmax and top-k comparisons; computing it in
// fp64 and rounding once makes our pe the correctly-rounded true value,
// minimizing discrete-choice flips vs the numpy reference.
__global__ void k_pe(const float* __restrict__ h0,
                     const float* __restrict__ We1, const float* __restrict__ be1,
                     const float* __restrict__ We2, const float* __restrict__ be2,
                     float* __restrict__ pe){
  __shared__ double hid[2][128];
  int t = threadIdx.x;
  int lp = t >> 7, j = t & 127;
  size_t p = (size_t)blockIdx.x*2 + lp;
  const float* hr = h0 + p*DIN;
  double acc = (double)be1[j];
  #pragma unroll
  for (int k=0;k<DIN;++k) acc += (double)hr[k]*(double)We1[k*DDIM + j];
  hid[lp][j] = acc > 0.0 ? acc : expm1(acc);
  __syncthreads();
  double acc2 = (double)be2[j];
  #pragma unroll 8
  for (int k=0;k<DDIM;++k) acc2 += hid[lp][k]*(double)We2[k*DDIM + j];
  pe[p*DDIM + j] = (float)acc2;
}

// ---------------- LSH bin id: argmax over [pe@R10, -pe@R10] -----------------
// 4 lanes per point; fp64 accumulation (f32 products are exact in f64),
// rounded to f32 before the argmax compare to mirror numpy semantics.
__global__ void k_binid(const float* __restrict__ pe, const float* __restrict__ R,
                        int* __restrict__ bid){
  int tid = blockIdx.x*256 + threadIdx.x;   // grid sized so tid < 4*BN
  int p = tid >> 2, part = tid & 3;
  const float* pr = pe + (size_t)p*DDIM + part*32;
  double m[10];
  #pragma unroll
  for (int j=0;j<10;++j) m[j] = 0.0;
  #pragma unroll 4
  for (int k=0;k<32;++k){
    double v = (double)pr[k];
    const float* rr = R + (size_t)(part*32 + k)*100;  // R (128,100) row-major, cols 0..9
    #pragma unroll
    for (int j=0;j<10;++j) m[j] += v*(double)rr[j];
  }
  #pragma unroll
  for (int j=0;j<10;++j){
    m[j] += __shfl_xor(m[j], 1);
    m[j] += __shfl_xor(m[j], 2);
  }
  if (part == 0){
    float mf[10];
    #pragma unroll
    for (int j=0;j<10;++j) mf[j] = (float)m[j];
    float bv = -1e30f; int bi = 0;
    #pragma unroll
    for (int j=0;j<20;++j){
      float v = (j<10) ? mf[j] : -mf[j-10];
      if (v > bv){ bv = v; bi = j; }   // strict > : first-max = jnp.argmax
    }
    bid[p] = bi;
  }
}

// ---------------- stable counting sort -> order (permutation) ---------------
// one block per (batch, bin); replicates stable argsort of integer keys.
__global__ void k_place(const int* __restrict__ binid, int* __restrict__ order){
  int b = blockIdx.x / NBINS, mybin = blockIdx.x % NBINS;
  const int* bid = binid + (size_t)b*NN;
  int t = threadIdx.x;
  __shared__ int wsum[4];
  __shared__ int wtot[4];
  __shared__ int sOff;
  // offset = #points with smaller bin id
  int c = 0;
  for (int i = t; i < NN; i += 256) c += (bid[i] < mybin) ? 1 : 0;
  #pragma unroll
  for (int o=32;o;o>>=1) c += __shfl_xor(c, o);
  if ((t & 63) == 0) wsum[t >> 6] = c;
  __syncthreads();
  if (t == 0) sOff = wsum[0]+wsum[1]+wsum[2]+wsum[3];
  __syncthreads();
  int base = sOff;
  int lane = t & 63, w = t >> 6;
  for (int ch = 0; ch < NN; ch += 256){
    int i = ch + t;
    bool flag = (i < NN) && (bid[i] == mybin);
    unsigned long long bal = __ballot(flag);
    int pre = __popcll(bal & ((1ull << lane) - 1ull));
    if (lane == 0) wtot[w] = __popcll(bal);
    __syncthreads();
    int woff = 0;
    #pragma unroll
    for (int ww=0; ww<4; ++ww) if (ww < w) woff += wtot[ww];
    if (flag) order[(size_t)b*NN + base + woff + pre] = i;
    base += wtot[0]+wtot[1]+wtot[2]+wtot[3];
    __syncthreads();
  }
}

// ---------------- per-bin dense sim + top-16, row-owner layout --------------
// block = (batch, bin, row-tile of 64). Thread t owns row lane=t&63 and
// column-quarter q=t>>6: double acc[16] per thread. colT reads are
// wave-uniform (broadcast, conflict-free); rowT reads are consecutive-lane
// (2-way aliasing, free). Selection is thread-local on f32 sigmoid values
// with first-index tie-break (matches lax.top_k); final 4-way quarter merge
// reuses the tile LDS. FP accumulation order identical to the verified
// Round-5 kernel -> bit-identical selections.
#define TPAD 68
__global__ void __launch_bounds__(256)
k_topk(const float* __restrict__ pe, const int* __restrict__ order,
       float* __restrict__ valk, int* __restrict__ idxk){
  __shared__ float rowT[64][TPAD];   // [k_local][row]
  __shared__ float colT[64][TPAD];   // [k_local][col]
  __shared__ int ordRow[64];
  __shared__ int ordCol[64];
  int blk = blockIdx.x;
  int b   = blk / (NBINS*10);
  int rem = blk % (NBINS*10);
  int bin = rem / 10, rt = rem % 10;
  int r0 = rt*64;
  int t = threadIdx.x;
  int lane = t & 63;    // owned row within the 64-row tile
  int q    = t >> 6;    // owned column quarter (16 cols)
  const float* peb = pe + (size_t)b*NN*DDIM;
  const int* ob = order + (size_t)b*NN + (size_t)bin*BS;
  if (t < 64) ordRow[t] = ob[r0 + t];

  float tv[16]; int ti[16];
  #pragma unroll
  for (int j=0;j<16;++j){ tv[j] = -1e30f; ti[j] = 1<<20; }
  float wv = -1e30f; int wi = 1<<20; int wpos = 0;

  for (int ct = 0; ct < 10; ++ct){
    if (t < 64) ordCol[t] = ob[ct*64 + t];
    double acc[16];
    #pragma unroll
    for (int j=0;j<16;++j) acc[j] = 0.0;
    #pragma unroll
    for (int kh = 0; kh < 2; ++kh){
      __syncthreads();
      for (int l=t; l<4096; l+=256){
        int rr = l >> 6, kk = l & 63;
        rowT[kk][rr] = peb[(size_t)ordRow[rr]*DDIM + kh*64 + kk];
      }
      for (int l=t; l<4096; l+=256){
        int cc = l >> 6, kk = l & 63;
        colT[kk][cc] = peb[(size_t)ordCol[cc]*DDIM + kh*64 + kk];
      }
      __syncthreads();
      #pragma unroll 2
      for (int kk=0; kk<64; ++kk){
        double a = (double)rowT[kk][lane];
        float4 w0 = *(const float4*)&colT[kk][16*q];
        float4 w1 = *(const float4*)&colT[kk][16*q + 4];
        float4 w2 = *(const float4*)&colT[kk][16*q + 8];
        float4 w3 = *(const float4*)&colT[kk][16*q + 12];
        acc[0]  += a*(double)w0.x; acc[1]  += a*(double)w0.y;
        acc[2]  += a*(double)w0.z; acc[3]  += a*(double)w0.w;
        acc[4]  += a*(double)w1.x; acc[5]  += a*(double)w1.y;
        acc[6]  += a*(double)w1.z; acc[7]  += a*(double)w1.w;
        acc[8]  += a*(double)w2.x; acc[9]  += a*(double)w2.y;
        acc[10] += a*(double)w2.z; acc[11] += a*(double)w2.w;
        acc[12] += a*(double)w3.x; acc[13] += a*(double)w3.y;
        acc[14] += a*(double)w3.z; acc[15] += a*(double)w3.w;
      }
    }
    // selection: 16 candidates (this thread's quarter of this ct tile)
    #pragma unroll
    for (int j=0;j<16;++j){
      float v = sigf((float)acc[j]);
      int gc = ct*64 + 16*q + j;
      bool better = (v > wv) || (v == wv && gc < wi);
      if (better){
        #pragma unroll
        for (int u=0;u<16;++u){ if (u == wpos){ tv[u] = v; ti[u] = gc; } }
        wv = tv[0]; wi = ti[0]; wpos = 0;
        #pragma unroll
        for (int u=1;u<16;++u){
          bool worse = (tv[u] < wv) || (tv[u] == wv && ti[u] > wi);
          if (worse){ wv = tv[u]; wi = ti[u]; wpos = u; }
        }
      }
    }
  }
  // ---- merge the 4 per-quarter lists per row (reuse tile LDS) ----
  __syncthreads();
  float* mv = (float*)&rowT[0][0];   // [64][49] values
  int*   mi = (int*)  &colT[0][0];   // [64][49] indices
  const int MS = 49;                 // odd stride -> conflict-free
  if (q > 0){
    #pragma unroll
    for (int j=0;j<16;++j){
      mv[lane*MS + (q-1)*16 + j] = tv[j];
      mi[lane*MS + (q-1)*16 + j] = ti[j];
    }
  }
  __syncthreads();
  if (q == 0){
    for (int j=0;j<48;++j){
      float v = mv[lane*MS + j];
      int gc  = mi[lane*MS + j];
      bool better = (v > wv) || (v == wv && gc < wi);
      if (better){
        #pragma unroll
        for (int u=0;u<16;++u){ if (u == wpos){ tv[u] = v; ti[u] = gc; } }
        wv = tv[0]; wi = ti[0]; wpos = 0;
        #pragma unroll
        for (int u=1;u<16;++u){
          bool worse = (tv[u] < wv) || (tv[u] == wv && ti[u] > wi);
          if (worse){ wv = tv[u]; wi = ti[u]; wpos = u; }
        }
      }
    }
    size_t base = (((size_t)(b*NBINS + bin))*BS + r0 + lane)*KNB;
    #pragma unroll
    for (int j=0;j<16;++j){ valk[base + j] = tv[j]; idxk[base + j] = ti[j]; }
  }
}

// -------- per-node edge-FFN partials: spart = bd1 + h0@Wd1[0:23],
//          dpart = h0@Wd1[23:46]  (each (BN,128)) -----------------------------
__global__ void k_epart(const float* __restrict__ h0,
                        const float* __restrict__ Wd1, const float* __restrict__ bd1,
                        float* __restrict__ spart, float* __restrict__ dpart){
  int t = threadIdx.x;
  int lp = t >> 7, j = t & 127;
  size_t p = (size_t)blockIdx.x*2 + lp;
  const float* hr = h0 + p*DIN;
  float sa = bd1[j];
  float da = 0.f;
  #pragma unroll
  for (int k=0;k<DIN;++k){
    float x = hr[k];
    sa += x*Wd1[k*128 + j];
    da += x*Wd1[(DIN+k)*128 + j];
  }
  spart[p*128 + j] = sa;
  dpart[p*128 + j] = da;
}

// ---------------- edge FFN (decomposed): one wave per edge ------------------
__global__ void k_edges(const float* __restrict__ spart, const float* __restrict__ dpart,
                        const int* __restrict__ order,
                        const float* __restrict__ valk, const int* __restrict__ idxk,
                        const float* __restrict__ Wd1, const float* __restrict__ Wd2,
                        const float* __restrict__ bd2,
                        float* __restrict__ wgt, int* __restrict__ dste){
  int lane = threadIdx.x & 63;
  size_t e = (size_t)blockIdx.x*4 + (threadIdx.x >> 6);
  int b  = (int)(e / EE);
  int eb = (int)(e % EE);
  int bin = eb / (BS*KNB);
  int rem = eb % (BS*KNB);
  int i  = rem / KNB;
  int kk = rem % KNB;
  const int* ob = order + (size_t)b*NN + (size_t)bin*BS;
  int src = ob[i];
  size_t tkb = ((size_t)(b*NBINS + bin)*BS + i)*KNB + kk;
  int ip = idxk[tkb];
  int dst = ob[ip];
  float dv = valk[tkb];
  size_t gs = ((size_t)b*NN + src)*128;
  size_t gd = ((size_t)b*NN + dst)*128;
  float a1 = spart[gs + lane]      + dpart[gd + lane]      + dv*Wd1[46*128 + lane];
  float a2 = spart[gs + 64 + lane] + dpart[gd + 64 + lane] + dv*Wd1[46*128 + 64 + lane];
  float ptl = eluf(a1)*Wd2[lane] + eluf(a2)*Wd2[lane + 64];
  #pragma unroll
  for (int o=32;o;o>>=1) ptl += __shfl_xor(ptl, o);
  if (lane == 0){
    wgt[e]  = sigf(ptl + bd2[0]);
    dste[e] = dst;
  }
}

// ---------------- degree -> norm (per node) ---------------------------------
__global__ void k_deg(const float* __restrict__ wgt, const int* __restrict__ order,
                      float* __restrict__ nrm){
  int id = blockIdx.x*256 + threadIdx.x;
  if (id >= BN) return;
  int b = id / NN;
  int p = id % NN;
  const float* w = wgt + (size_t)b*EE + (size_t)p*KNB;
  float s = 0.f;
  #pragma unroll
  for (int k=0;k<KNB;++k) s += fabsf(w[k]);
  int node = order[id];
  nrm[(size_t)b*NN + node] = 1.f/sqrtf(s + 1e-6f);
}

// ---------------- encoder: selu(h0@Wenc+benc), 8 points / block -------------
__global__ void k_enc(const float* __restrict__ h0, const float* __restrict__ Wenc,
                      const float* __restrict__ benc, float* __restrict__ xe){
  __shared__ float hs[8][DIN+1];
  size_t p0 = (size_t)blockIdx.x*8;
  int t = threadIdx.x;
  if (t < 8*DIN){
    int pp = t / DIN, ff = t - pp*DIN;
    hs[pp][ff] = h0[(p0+pp)*DIN + ff];
  }
  float wreg[DIN];
  #pragma unroll
  for (int k=0;k<DIN;++k) wreg[k] = Wenc[k*HID + t];
  float bb = benc[t];
  __syncthreads();
  #pragma unroll
  for (int pp=0;pp<8;++pp){
    float acc = bb;
    #pragma unroll
    for (int k=0;k<DIN;++k) acc += hs[pp][k]*wreg[k];
    xe[(p0+pp)*HID + t] = seluf(acc);
  }
}

// ------- 128x128-tile GEMM: (BN x 256) @ (256 x 256), 8x8 per thread --------
// MODE 0: C=A@W ; 1: C=(A@W)*rs[row] ; 2: sigmoid(A@W+b) ; 3: selu(A@W+b)
template<int MODE>
__global__ void __launch_bounds__(256)
k_gemm128(const float* __restrict__ A, const float* __restrict__ W,
          const float* __restrict__ bias, const float* __restrict__ rs,
          float* __restrict__ C){
  __shared__ float As[16][132];   // [k][m] transposed A tile
  __shared__ float Ws[16][132];   // [k][n]
  int t = threadIdx.x;
  int m0 = blockIdx.x*128, n0 = blockIdx.y*128;
  int tx = t & 15, ty = t >> 4;
  float acc[8][8];
  #pragma unroll
  for (int i=0;i<8;++i){
    #pragma unroll
    for (int j=0;j<8;++j) acc[i][j] = 0.f;
  }
  for (int kt=0; kt<16; ++kt){
    int k0 = kt*16;
    __syncthreads();
    #pragma unroll
    for (int l=0;l<8;++l){
      int idx = t + l*256;
      int m = idx >> 4, kk = idx & 15;
      As[kk][m] = A[((size_t)(m0+m))*HID + k0 + kk];
    }
    #pragma unroll
    for (int l=0;l<8;++l){
      int idx = t + l*256;
      int kk = idx >> 7, nn = idx & 127;
      Ws[kk][nn] = W[((size_t)(k0+kk))*HID + n0 + nn];
    }
    __syncthreads();
    #pragma unroll
    for (int kk=0;kk<16;++kk){
      float4 a0 = *(const float4*)&As[kk][4*ty];
      float4 a1 = *(const float4*)&As[kk][64 + 4*ty];
      float4 w0 = *(const float4*)&Ws[kk][4*tx];
      float4 w1 = *(const float4*)&Ws[kk][64 + 4*tx];
      float av[8], wv[8];
      av[0]=a0.x; av[1]=a0.y; av[2]=a0.z; av[3]=a0.w;
      av[4]=a1.x; av[5]=a1.y; av[6]=a1.z; av[7]=a1.w;
      wv[0]=w0.x; wv[1]=w0.y; wv[2]=w0.z; wv[3]=w0.w;
      wv[4]=w1.x; wv[5]=w1.y; wv[6]=w1.z; wv[7]=w1.w;
      #pragma unroll
      for (int i=0;i<8;++i){
        #pragma unroll
        for (int j=0;j<8;++j) acc[i][j] += av[i]*wv[j];
      }
    }
  }
  float b0[8];
  if (MODE == 2 || MODE == 3){
    #pragma unroll
    for (int j=0;j<8;++j) b0[j] = bias[n0 + (j<4 ? 4*tx+j : 60+4*tx+j)];
  }
  #pragma unroll
  for (int i=0;i<8;++i){
    int row = m0 + (i<4 ? 4*ty+i : 60+4*ty+i);
    float sc = (MODE == 1) ? rs[row] : 1.f;
    float v[8];
    #pragma unroll
    for (int j=0;j<8;++j){
      float x = acc[i][j];
      if (MODE == 2 || MODE == 3) x += b0[j];
      if (MODE == 1) x *= sc;
      if (MODE == 2) x = sigf(x);
      if (MODE == 3) x = seluf(x);
      v[j] = x;
    }
    float4 r0; r0.x=v[0]; r0.y=v[1]; r0.z=v[2]; r0.w=v[3];
    float4 r1; r1.x=v[4]; r1.y=v[5]; r1.z=v[6]; r1.w=v[7];
    *(float4*)&C[(size_t)row*HID + n0 + 4*tx]      = r0;
    *(float4*)&C[(size_t)row*HID + n0 + 64 + 4*tx] = r1;
  }
}

// ---------------- GHConv combine --------------------------------------------
__global__ void k_combine(const float* __restrict__ fh, const float* __restrict__ xh,
                          const float* __restrict__ gate, const float* __restrict__ wgt,
                          const int* __restrict__ dste, const int* __restrict__ order,
                          const float* __restrict__ nrm, float* __restrict__ xg){
  __shared__ float ew[KNB];
  __shared__ int   ed[KNB];
  int blk = blockIdx.x;
  int b = blk / NN, p = blk % NN;
  int t = threadIdx.x;
  if (t < KNB){
    size_t e = (size_t)b*EE + (size_t)p*KNB + t;
    ew[t] = wgt[e];
    ed[t] = dste[e];
  }
  __syncthreads();
  int src = order[(size_t)b*NN + p];
  float nr = nrm[(size_t)b*NN + src];
  size_t base = (size_t)b*NN*HID;
  float acc = 0.f;
  #pragma unroll
  for (int k=0;k<KNB;++k) acc += ew[k]*fh[base + (size_t)ed[k]*HID + t];
  acc *= nr;
  size_t o = base + (size_t)src*HID + t;
  float g = gate[o];
  xg[o] = seluf(g*acc + (1.f - g)*xh[o]);
}

// ---------------- output head: one wave per point ---------------------------
__global__ void k_head(const float* __restrict__ xd, const float* __restrict__ Wout,
                       const float* __restrict__ bout, float* __restrict__ out){
  int lane = threadIdx.x & 63;
  size_t p = (size_t)blockIdx.x*4 + (threadIdx.x >> 6);
  float4 x = *(const float4*)&xd[p*HID + lane*4];
  float a0 = 0.f, a1 = 0.f, a2 = 0.f;
  const float* wr = Wout + lane*4*3;
  a0 += x.x*wr[0]; a1 += x.x*wr[1]; a2 += x.x*wr[2];
  a0 += x.y*wr[3]; a1 += x.y*wr[4]; a2 += x.y*wr[5];
  a0 += x.z*wr[6]; a1 += x.z*wr[7]; a2 += x.z*wr[8];
  a0 += x.w*wr[9]; a1 += x.w*wr[10]; a2 += x.w*wr[11];
  #pragma unroll
  for (int o=32;o;o>>=1){
    a0 += __shfl_xor(a0, o);
    a1 += __shfl_xor(a1, o);
    a2 += __shfl_xor(a2, o);
  }
  if (lane == 0){
    out[p*3 + 0] = a0 + bout[0];
    out[p*3 + 1] = a1 + bout[1];
    out[p*3 + 2] = a2 + bout[2];
  }
}

// ---------------------------------------------------------------------------
extern "C" void kernel_launch(void* const* d_in, const int* in_sizes, int n_in,
                              void* d_out, int out_size, void* d_ws, size_t ws_size,
                              hipStream_t stream){
  (void)in_sizes; (void)n_in; (void)out_size; (void)ws_size;
  const float* X    = (const float*)d_in[0];
  const float* We1  = (const float*)d_in[1];
  const float* be1  = (const float*)d_in[2];
  const float* We2  = (const float*)d_in[3];
  const float* be2  = (const float*)d_in[4];
  const float* Wd1  = (const float*)d_in[5];
  const float* bd1  = (const float*)d_in[6];
  const float* Wd2  = (const float*)d_in[7];
  const float* bd2  = (const float*)d_in[8];
  const float* R    = (const float*)d_in[9];
  const float* Wenc = (const float*)d_in[10];
  const float* benc = (const float*)d_in[11];
  const float* Wt   = (const float*)d_in[12];
  const float* bt   = (const float*)d_in[13];
  const float* Wh   = (const float*)d_in[14];
  const float* theta= (const float*)d_in[15];
  const float* Wdec = (const float*)d_in[16];
  const float* bdec = (const float*)d_in[17];
  const float* Wout = (const float*)d_in[18];
  const float* bout = (const float*)d_in[19];
  float* out = (float*)d_out;

  char* ws = (char*)d_ws; size_t off = 0;
  auto alloc = [&](size_t bytes)->void*{
    void* p = ws + off; off = (off + bytes + 255) & ~(size_t)255; return p;
  };
  float* h0   = (float*)alloc((size_t)BN*DIN*4);
  float* pe   = (float*)alloc((size_t)BN*DDIM*4);
  int*   bid  = (int*)  alloc((size_t)BN*4);
  int*   order= (int*)  alloc((size_t)BN*4);
  float* valk = (float*)alloc((size_t)BB*NBINS*BS*KNB*4);
  int*   idxk = (int*)  alloc((size_t)BB*NBINS*BS*KNB*4);
  float* wgt  = (float*)alloc((size_t)BB*EE*4);
  int*   dste = (int*)  alloc((size_t)BB*EE*4);
  float* nrm  = (float*)alloc((size_t)BN*4);
  float* xe   = (float*)alloc((size_t)BN*HID*4);
  float* fh   = (float*)alloc((size_t)BN*HID*4);
  float* xh   = (float*)alloc((size_t)BN*HID*4);
  float* gate = (float*)alloc((size_t)BN*HID*4);
  // aliases (stream-ordered; aliased buffer dead before alias written):
  float* spart = pe;   // (BN,128) == pe exactly; pe dead after k_topk
  float* dpart = xe;   // (BN,128) fits in xe; xe written by k_enc AFTER k_edges
  float* xg    = xe;   // combine output; xe dead after the 3 GHConv gemms
  float* xd    = fh;   // decoder output; fh dead after k_combine

  k_h0   <<<(BN*DIN + 255)/256, 256, 0, stream>>>(X, h0);
  k_pe   <<<BN/2, 256, 0, stream>>>(h0, We1, be1, We2, be2, pe);
  k_binid<<<BN*4/256, 256, 0, stream>>>(pe, R, bid);
  k_place<<<BB*NBINS, 256, 0, stream>>>(bid, order);
  k_topk <<<BB*NBINS*10, 256, 0, stream>>>(pe, order, valk, idxk);
  k_epart<<<BN/2, 256, 0, stream>>>(h0, Wd1, bd1, spart, dpart);
  k_edges<<<BB*EE/4, 256, 0, stream>>>(spart, dpart, order, valk, idxk, Wd1, Wd2, bd2, wgt, dste);
  k_deg  <<<(BN + 255)/256, 256, 0, stream>>>(wgt, order, nrm);
  k_enc  <<<BN/8, 256, 0, stream>>>(h0, Wenc, benc, xe);
  dim3 gg(BN/128, HID/128);
  k_gemm128<0><<<gg, 256, 0, stream>>>(xe, Wh,    nullptr, nullptr, xh);
  k_gemm128<1><<<gg, 256, 0, stream>>>(xe, theta, nullptr, nrm,     fh);
  k_gemm128<2><<<gg, 256, 0, stream>>>(xe, Wt,    bt,      nullptr, gate);
  k_combine<<<BN, 256, 0, stream>>>(fh, xh, gate, wgt, dste, order, nrm, xg);
  k_gemm128<3><<<gg, 256, 0, stream>>>(xg, Wdec,  bdec,    nullptr, xd);
  k_head <<<BN/4, 256, 0, stream>>>(xd, Wout, bout, out);
}

// Round 10
// 1644.015 us; speedup vs baseline: 1.1035x; 1.0620x over previous
//
#include <hip/hip_runtime.h>
#include <cstdint>
#include <cstddef>
#include <math.h>

#define BB    4
#define NN    12800
#define FF    16
#define DIN   23
#define NCLS  8
#define DDIM  128
#define HID   256
#define NBINS 20
#define BS    640
#define KNB   16
#define EE    (NN*KNB)   /* 204800 edges per batch */
#define BN    (BB*NN)    /* 51200 points total */

__device__ __forceinline__ float eluf(float x){ return x > 0.f ? x : expm1f(x); }
__device__ __forceinline__ float seluf(float x){
  const float a = 1.6732632423543772f, s = 1.0507009873554805f;
  return x > 0.f ? s*x : s*a*expm1f(x);
}
__device__ __forceinline__ float sigf(float x){ return 1.f/(1.f+expf(-x)); }

// ---------------- h0 = [one_hot(X[:,:,0],8), X[:,:,1:]] -> (BN,23) ----------
__global__ void k_h0(const float* __restrict__ X, float* __restrict__ h0){
  int id = blockIdx.x*256 + threadIdx.x;
  if (id >= BN*DIN) return;
  int p = id / DIN, f = id % DIN;
  const float* xr = X + (size_t)p*FF;
  float v;
  if (f < NCLS){
    int cls = (int)xr[0];
    v = (f == cls) ? 1.f : 0.f;
  } else {
    v = xr[f - NCLS + 1];
  }
  h0[id] = v;
}

// ------ pe = elu(h0@We1+be1)@We2+be2 -> (BN,128), fp64 internally -----------
// pe feeds the LSH argmax whose flips shift the ENTIRE argsort permutation
// (catastrophic downstream). fp64-then-round makes our pe correctly rounded.
__global__ void k_pe(const float* __restrict__ h0,
                     const float* __restrict__ We1, const float* __restrict__ be1,
                     const float* __restrict__ We2, const float* __restrict__ be2,
                     float* __restrict__ pe){
  __shared__ double hid[2][128];
  int t = threadIdx.x;
  int lp = t >> 7, j = t & 127;
  size_t p = (size_t)blockIdx.x*2 + lp;
  const float* hr = h0 + p*DIN;
  double acc = (double)be1[j];
  #pragma unroll
  for (int k=0;k<DIN;++k) acc += (double)hr[k]*(double)We1[k*DDIM + j];
  hid[lp][j] = acc > 0.0 ? acc : expm1(acc);
  __syncthreads();
  double acc2 = (double)be2[j];
  #pragma unroll 8
  for (int k=0;k<DDIM;++k) acc2 += hid[lp][k]*(double)We2[k*DDIM + j];
  pe[p*DDIM + j] = (float)acc2;
}

// ---------------- LSH bin id: argmax over [pe@R10, -pe@R10] -----------------
// 4 lanes per point; fp64 accumulation (f32 products are exact in f64),
// rounded to f32 before the argmax compare to mirror numpy semantics.
__global__ void k_binid(const float* __restrict__ pe, const float* __restrict__ R,
                        int* __restrict__ bid){
  int tid = blockIdx.x*256 + threadIdx.x;   // grid sized so tid < 4*BN
  int p = tid >> 2, part = tid & 3;
  const float* pr = pe + (size_t)p*DDIM + part*32;
  double m[10];
  #pragma unroll
  for (int j=0;j<10;++j) m[j] = 0.0;
  #pragma unroll 4
  for (int k=0;k<32;++k){
    double v = (double)pr[k];
    const float* rr = R + (size_t)(part*32 + k)*100;  // R (128,100) row-major, cols 0..9
    #pragma unroll
    for (int j=0;j<10;++j) m[j] += v*(double)rr[j];
  }
  #pragma unroll
  for (int j=0;j<10;++j){
    m[j] += __shfl_xor(m[j], 1);
    m[j] += __shfl_xor(m[j], 2);
  }
  if (part == 0){
    float mf[10];
    #pragma unroll
    for (int j=0;j<10;++j) mf[j] = (float)m[j];
    float bv = -1e30f; int bi = 0;
    #pragma unroll
    for (int j=0;j<20;++j){
      float v = (j<10) ? mf[j] : -mf[j-10];
      if (v > bv){ bv = v; bi = j; }   // strict > : first-max = jnp.argmax
    }
    bid[p] = bi;
  }
}

// ---------------- stable counting sort -> order (permutation) ---------------
// one block per (batch, bin); replicates stable argsort of integer keys.
__global__ void k_place(const int* __restrict__ binid, int* __restrict__ order){
  int b = blockIdx.x / NBINS, mybin = blockIdx.x % NBINS;
  const int* bid = binid + (size_t)b*NN;
  int t = threadIdx.x;
  __shared__ int wsum[4];
  __shared__ int wtot[4];
  __shared__ int sOff;
  // offset = #points with smaller bin id
  int c = 0;
  for (int i = t; i < NN; i += 256) c += (bid[i] < mybin) ? 1 : 0;
  #pragma unroll
  for (int o=32;o;o>>=1) c += __shfl_xor(c, o);
  if ((t & 63) == 0) wsum[t >> 6] = c;
  __syncthreads();
  if (t == 0) sOff = wsum[0]+wsum[1]+wsum[2]+wsum[3];
  __syncthreads();
  int base = sOff;
  int lane = t & 63, w = t >> 6;
  for (int ch = 0; ch < NN; ch += 256){
    int i = ch + t;
    bool flag = (i < NN) && (bid[i] == mybin);
    unsigned long long bal = __ballot(flag);
    int pre = __popcll(bal & ((1ull << lane) - 1ull));
    if (lane == 0) wtot[w] = __popcll(bal);
    __syncthreads();
    int woff = 0;
    #pragma unroll
    for (int ww=0; ww<4; ++ww) if (ww < w) woff += wtot[ww];
    if (flag) order[(size_t)b*NN + base + woff + pre] = i;
    base += wtot[0]+wtot[1]+wtot[2]+wtot[3];
    __syncthreads();
  }
}

// ---------------- per-bin dense sim + top-16, row-owner layout --------------
// fp32 accumulation: top-k flips are localized (one near-equal edge swap);
// intra-top-16 permutations are output-invariant. Thread t owns row lane,
// col-quarter q; float acc[16]. No converts in the hot loop.
#define TPAD 68
__global__ void __launch_bounds__(256)
k_topk(const float* __restrict__ pe, const int* __restrict__ order,
       float* __restrict__ valk, int* __restrict__ idxk){
  __shared__ float rowT[64][TPAD];   // [k_local][row]
  __shared__ float colT[64][TPAD];   // [k_local][col]
  __shared__ int ordRow[64];
  __shared__ int ordCol[64];
  int blk = blockIdx.x;
  int b   = blk / (NBINS*10);
  int rem = blk % (NBINS*10);
  int bin = rem / 10, rt = rem % 10;
  int r0 = rt*64;
  int t = threadIdx.x;
  int lane = t & 63;    // owned row within the 64-row tile
  int q    = t >> 6;    // owned column quarter (16 cols)
  const float* peb = pe + (size_t)b*NN*DDIM;
  const int* ob = order + (size_t)b*NN + (size_t)bin*BS;
  if (t < 64) ordRow[t] = ob[r0 + t];

  float tv[16]; int ti[16];
  #pragma unroll
  for (int j=0;j<16;++j){ tv[j] = -1e30f; ti[j] = 1<<20; }
  float wv = -1e30f; int wi = 1<<20; int wpos = 0;

  for (int ct = 0; ct < 10; ++ct){
    if (t < 64) ordCol[t] = ob[ct*64 + t];
    float acc[16];
    #pragma unroll
    for (int j=0;j<16;++j) acc[j] = 0.f;
    #pragma unroll
    for (int kh = 0; kh < 2; ++kh){
      __syncthreads();
      for (int l=t; l<4096; l+=256){
        int rr = l >> 6, kk = l & 63;
        rowT[kk][rr] = peb[(size_t)ordRow[rr]*DDIM + kh*64 + kk];
      }
      for (int l=t; l<4096; l+=256){
        int cc = l >> 6, kk = l & 63;
        colT[kk][cc] = peb[(size_t)ordCol[cc]*DDIM + kh*64 + kk];
      }
      __syncthreads();
      #pragma unroll 4
      for (int kk=0; kk<64; ++kk){
        float a = rowT[kk][lane];
        float4 w0 = *(const float4*)&colT[kk][16*q];
        float4 w1 = *(const float4*)&colT[kk][16*q + 4];
        float4 w2 = *(const float4*)&colT[kk][16*q + 8];
        float4 w3 = *(const float4*)&colT[kk][16*q + 12];
        acc[0]  += a*w0.x; acc[1]  += a*w0.y; acc[2]  += a*w0.z; acc[3]  += a*w0.w;
        acc[4]  += a*w1.x; acc[5]  += a*w1.y; acc[6]  += a*w1.z; acc[7]  += a*w1.w;
        acc[8]  += a*w2.x; acc[9]  += a*w2.y; acc[10] += a*w2.z; acc[11] += a*w2.w;
        acc[12] += a*w3.x; acc[13] += a*w3.y; acc[14] += a*w3.z; acc[15] += a*w3.w;
      }
    }
    // selection: 16 candidates (this thread's quarter of this ct tile)
    #pragma unroll
    for (int j=0;j<16;++j){
      float v = sigf(acc[j]);
      int gc = ct*64 + 16*q + j;
      bool better = (v > wv) || (v == wv && gc < wi);
      if (better){
        #pragma unroll
        for (int u=0;u<16;++u){ if (u == wpos){ tv[u] = v; ti[u] = gc; } }
        wv = tv[0]; wi = ti[0]; wpos = 0;
        #pragma unroll
        for (int u=1;u<16;++u){
          bool worse = (tv[u] < wv) || (tv[u] == wv && ti[u] > wi);
          if (worse){ wv = tv[u]; wi = ti[u]; wpos = u; }
        }
      }
    }
  }
  // ---- merge the 4 per-quarter lists per row (reuse tile LDS) ----
  __syncthreads();
  float* mv = (float*)&rowT[0][0];   // [64][49] values
  int*   mi = (int*)  &colT[0][0];   // [64][49] indices
  const int MS = 49;                 // odd stride -> conflict-free
  if (q > 0){
    #pragma unroll
    for (int j=0;j<16;++j){
      mv[lane*MS + (q-1)*16 + j] = tv[j];
      mi[lane*MS + (q-1)*16 + j] = ti[j];
    }
  }
  __syncthreads();
  if (q == 0){
    for (int j=0;j<48;++j){
      float v = mv[lane*MS + j];
      int gc  = mi[lane*MS + j];
      bool better = (v > wv) || (v == wv && gc < wi);
      if (better){
        #pragma unroll
        for (int u=0;u<16;++u){ if (u == wpos){ tv[u] = v; ti[u] = gc; } }
        wv = tv[0]; wi = ti[0]; wpos = 0;
        #pragma unroll
        for (int u=1;u<16;++u){
          bool worse = (tv[u] < wv) || (tv[u] == wv && ti[u] > wi);
          if (worse){ wv = tv[u]; wi = ti[u]; wpos = u; }
        }
      }
    }
    size_t base = (((size_t)(b*NBINS + bin))*BS + r0 + lane)*KNB;
    #pragma unroll
    for (int j=0;j<16;++j){ valk[base + j] = tv[j]; idxk[base + j] = ti[j]; }
  }
}

// -------- per-node edge-FFN partials: spart = bd1 + h0@Wd1[0:23],
//          dpart = h0@Wd1[23:46]  (each (BN,128)) -----------------------------
__global__ void k_epart(const float* __restrict__ h0,
                        const float* __restrict__ Wd1, const float* __restrict__ bd1,
                        float* __restrict__ spart, float* __restrict__ dpart){
  int t = threadIdx.x;
  int lp = t >> 7, j = t & 127;
  size_t p = (size_t)blockIdx.x*2 + lp;
  const float* hr = h0 + p*DIN;
  float sa = bd1[j];
  float da = 0.f;
  #pragma unroll
  for (int k=0;k<DIN;++k){
    float x = hr[k];
    sa += x*Wd1[k*128 + j];
    da += x*Wd1[(DIN+k)*128 + j];
  }
  spart[p*128 + j] = sa;
  dpart[p*128 + j] = da;
}

// ---------------- edge FFN (decomposed): one wave per edge ------------------
__global__ void k_edges(const float* __restrict__ spart, const float* __restrict__ dpart,
                        const int* __restrict__ order,
                        const float* __restrict__ valk, const int* __restrict__ idxk,
                        const float* __restrict__ Wd1, const float* __restrict__ Wd2,
                        const float* __restrict__ bd2,
                        float* __restrict__ wgt, int* __restrict__ dste){
  int lane = threadIdx.x & 63;
  size_t e = (size_t)blockIdx.x*4 + (threadIdx.x >> 6);
  int b  = (int)(e / EE);
  int eb = (int)(e % EE);
  int bin = eb / (BS*KNB);
  int rem = eb % (BS*KNB);
  int i  = rem / KNB;
  int kk = rem % KNB;
  const int* ob = order + (size_t)b*NN + (size_t)bin*BS;
  int src = ob[i];
  size_t tkb = ((size_t)(b*NBINS + bin)*BS + i)*KNB + kk;
  int ip = idxk[tkb];
  int dst = ob[ip];
  float dv = valk[tkb];
  size_t gs = ((size_t)b*NN + src)*128;
  size_t gd = ((size_t)b*NN + dst)*128;
  float a1 = spart[gs + lane]      + dpart[gd + lane]      + dv*Wd1[46*128 + lane];
  float a2 = spart[gs + 64 + lane] + dpart[gd + 64 + lane] + dv*Wd1[46*128 + 64 + lane];
  float ptl = eluf(a1)*Wd2[lane] + eluf(a2)*Wd2[lane + 64];
  #pragma unroll
  for (int o=32;o;o>>=1) ptl += __shfl_xor(ptl, o);
  if (lane == 0){
    wgt[e]  = sigf(ptl + bd2[0]);
    dste[e] = dst;
  }
}

// ---------------- degree -> norm (per node) ---------------------------------
__global__ void k_deg(const float* __restrict__ wgt, const int* __restrict__ order,
                      float* __restrict__ nrm){
  int id = blockIdx.x*256 + threadIdx.x;
  if (id >= BN) return;
  int b = id / NN;
  int p = id % NN;
  const float* w = wgt + (size_t)b*EE + (size_t)p*KNB;
  float s = 0.f;
  #pragma unroll
  for (int k=0;k<KNB;++k) s += fabsf(w[k]);
  int node = order[id];
  nrm[(size_t)b*NN + node] = 1.f/sqrtf(s + 1e-6f);
}

// ---------------- encoder: selu(h0@Wenc+benc), 8 points / block -------------
__global__ void k_enc(const float* __restrict__ h0, const float* __restrict__ Wenc,
                      const float* __restrict__ benc, float* __restrict__ xe){
  __shared__ float hs[8][DIN+1];
  size_t p0 = (size_t)blockIdx.x*8;
  int t = threadIdx.x;
  if (t < 8*DIN){
    int pp = t / DIN, ff = t - pp*DIN;
    hs[pp][ff] = h0[(p0+pp)*DIN + ff];
  }
  float wreg[DIN];
  #pragma unroll
  for (int k=0;k<DIN;++k) wreg[k] = Wenc[k*HID + t];
  float bb = benc[t];
  __syncthreads();
  #pragma unroll
  for (int pp=0;pp<8;++pp){
    float acc = bb;
    #pragma unroll
    for (int k=0;k<DIN;++k) acc += hs[pp][k]*wreg[k];
    xe[(p0+pp)*HID + t] = seluf(acc);
  }
}

// ------- 128x128-tile GEMM: (BN x 256) @ (256 x 256), 8x8 per thread --------
// MODE 0: C=A@W ; 1: C=(A@W)*rs[row] ; 2: sigmoid(A@W+b) ; 3: selu(A@W+b)
template<int MODE>
__global__ void __launch_bounds__(256)
k_gemm128(const float* __restrict__ A, const float* __restrict__ W,
          const float* __restrict__ bias, const float* __restrict__ rs,
          float* __restrict__ C){
  __shared__ float As[16][132];   // [k][m] transposed A tile
  __shared__ float Ws[16][132];   // [k][n]
  int t = threadIdx.x;
  int m0 = blockIdx.x*128, n0 = blockIdx.y*128;
  int tx = t & 15, ty = t >> 4;
  float acc[8][8];
  #pragma unroll
  for (int i=0;i<8;++i){
    #pragma unroll
    for (int j=0;j<8;++j) acc[i][j] = 0.f;
  }
  for (int kt=0; kt<16; ++kt){
    int k0 = kt*16;
    __syncthreads();
    #pragma unroll
    for (int l=0;l<8;++l){
      int idx = t + l*256;
      int m = idx >> 4, kk = idx & 15;
      As[kk][m] = A[((size_t)(m0+m))*HID + k0 + kk];
    }
    #pragma unroll
    for (int l=0;l<8;++l){
      int idx = t + l*256;
      int kk = idx >> 7, nn = idx & 127;
      Ws[kk][nn] = W[((size_t)(k0+kk))*HID + n0 + nn];
    }
    __syncthreads();
    #pragma unroll
    for (int kk=0;kk<16;++kk){
      float4 a0 = *(const float4*)&As[kk][4*ty];
      float4 a1 = *(const float4*)&As[kk][64 + 4*ty];
      float4 w0 = *(const float4*)&Ws[kk][4*tx];
      float4 w1 = *(const float4*)&Ws[kk][64 + 4*tx];
      float av[8], wv[8];
      av[0]=a0.x; av[1]=a0.y; av[2]=a0.z; av[3]=a0.w;
      av[4]=a1.x; av[5]=a1.y; av[6]=a1.z; av[7]=a1.w;
      wv[0]=w0.x; wv[1]=w0.y; wv[2]=w0.z; wv[3]=w0.w;
      wv[4]=w1.x; wv[5]=w1.y; wv[6]=w1.z; wv[7]=w1.w;
      #pragma unroll
      for (int i=0;i<8;++i){
        #pragma unroll
        for (int j=0;j<8;++j) acc[i][j] += av[i]*wv[j];
      }
    }
  }
  float b0[8];
  if (MODE == 2 || MODE == 3){
    #pragma unroll
    for (int j=0;j<8;++j) b0[j] = bias[n0 + (j<4 ? 4*tx+j : 60+4*tx+j)];
  }
  #pragma unroll
  for (int i=0;i<8;++i){
    int row = m0 + (i<4 ? 4*ty+i : 60+4*ty+i);
    float sc = (MODE == 1) ? rs[row] : 1.f;
    float v[8];
    #pragma unroll
    for (int j=0;j<8;++j){
      float x = acc[i][j];
      if (MODE == 2 || MODE == 3) x += b0[j];
      if (MODE == 1) x *= sc;
      if (MODE == 2) x = sigf(x);
      if (MODE == 3) x = seluf(x);
      v[j] = x;
    }
    float4 r0; r0.x=v[0]; r0.y=v[1]; r0.z=v[2]; r0.w=v[3];
    float4 r1; r1.x=v[4]; r1.y=v[5]; r1.z=v[6]; r1.w=v[7];
    *(float4*)&C[(size_t)row*HID + n0 + 4*tx]      = r0;
    *(float4*)&C[(size_t)row*HID + n0 + 64 + 4*tx] = r1;
  }
}

// ---------------- GHConv combine --------------------------------------------
__global__ void k_combine(const float* __restrict__ fh, const float* __restrict__ xh,
                          const float* __restrict__ gate, const float* __restrict__ wgt,
                          const int* __restrict__ dste, const int* __restrict__ order,
                          const float* __restrict__ nrm, float* __restrict__ xg){
  __shared__ float ew[KNB];
  __shared__ int   ed[KNB];
  int blk = blockIdx.x;
  int b = blk / NN, p = blk % NN;
  int t = threadIdx.x;
  if (t < KNB){
    size_t e = (size_t)b*EE + (size_t)p*KNB + t;
    ew[t] = wgt[e];
    ed[t] = dste[e];
  }
  __syncthreads();
  int src = order[(size_t)b*NN + p];
  float nr = nrm[(size_t)b*NN + src];
  size_t base = (size_t)b*NN*HID;
  float acc = 0.f;
  #pragma unroll
  for (int k=0;k<KNB;++k) acc += ew[k]*fh[base + (size_t)ed[k]*HID + t];
  acc *= nr;
  size_t o = base + (size_t)src*HID + t;
  float g = gate[o];
  xg[o] = seluf(g*acc + (1.f - g)*xh[o]);
}

// ---------------- output head: one wave per point ---------------------------
__global__ void k_head(const float* __restrict__ xd, const float* __restrict__ Wout,
                       const float* __restrict__ bout, float* __restrict__ out){
  int lane = threadIdx.x & 63;
  size_t p = (size_t)blockIdx.x*4 + (threadIdx.x >> 6);
  float4 x = *(const float4*)&xd[p*HID + lane*4];
  float a0 = 0.f, a1 = 0.f, a2 = 0.f;
  const float* wr = Wout + lane*4*3;
  a0 += x.x*wr[0]; a1 += x.x*wr[1]; a2 += x.x*wr[2];
  a0 += x.y*wr[3]; a1 += x.y*wr[4]; a2 += x.y*wr[5];
  a0 += x.z*wr[6]; a1 += x.z*wr[7]; a2 += x.z*wr[8];
  a0 += x.w*wr[9]; a1 += x.w*wr[10]; a2 += x.w*wr[11];
  #pragma unroll
  for (int o=32;o;o>>=1){
    a0 += __shfl_xor(a0, o);
    a1 += __shfl_xor(a1, o);
    a2 += __shfl_xor(a2, o);
  }
  if (lane == 0){
    out[p*3 + 0] = a0 + bout[0];
    out[p*3 + 1] = a1 + bout[1];
    out[p*3 + 2] = a2 + bout[2];
  }
}

// ---------------------------------------------------------------------------
extern "C" void kernel_launch(void* const* d_in, const int* in_sizes, int n_in,
                              void* d_out, int out_size, void* d_ws, size_t ws_size,
                              hipStream_t stream){
  (void)in_sizes; (void)n_in; (void)out_size; (void)ws_size;
  const float* X    = (const float*)d_in[0];
  const float* We1  = (const float*)d_in[1];
  const float* be1  = (const float*)d_in[2];
  const float* We2  = (const float*)d_in[3];
  const float* be2  = (const float*)d_in[4];
  const float* Wd1  = (const float*)d_in[5];
  const float* bd1  = (const float*)d_in[6];
  const float* Wd2  = (const float*)d_in[7];
  const float* bd2  = (const float*)d_in[8];
  const float* R    = (const float*)d_in[9];
  const float* Wenc = (const float*)d_in[10];
  const float* benc = (const float*)d_in[11];
  const float* Wt   = (const float*)d_in[12];
  const float* bt   = (const float*)d_in[13];
  const float* Wh   = (const float*)d_in[14];
  const float* theta= (const float*)d_in[15];
  const float* Wdec = (const float*)d_in[16];
  const float* bdec = (const float*)d_in[17];
  const float* Wout = (const float*)d_in[18];
  const float* bout = (const float*)d_in[19];
  float* out = (float*)d_out;

  char* ws = (char*)d_ws; size_t off = 0;
  auto alloc = [&](size_t bytes)->void*{
    void* p = ws + off; off = (off + bytes + 255) & ~(size_t)255; return p;
  };
  float* h0   = (float*)alloc((size_t)BN*DIN*4);
  float* pe   = (float*)alloc((size_t)BN*DDIM*4);
  int*   bid  = (int*)  alloc((size_t)BN*4);
  int*   order= (int*)  alloc((size_t)BN*4);
  float* valk = (float*)alloc((size_t)BB*NBINS*BS*KNB*4);
  int*   idxk = (int*)  alloc((size_t)BB*NBINS*BS*KNB*4);
  float* wgt  = (float*)alloc((size_t)BB*EE*4);
  int*   dste = (int*)  alloc((size_t)BB*EE*4);
  float* nrm  = (float*)alloc((size_t)BN*4);
  float* xe   = (float*)alloc((size_t)BN*HID*4);
  float* fh   = (float*)alloc((size_t)BN*HID*4);
  float* xh   = (float*)alloc((size_t)BN*HID*4);
  float* gate = (float*)alloc((size_t)BN*HID*4);
  // aliases (stream-ordered; aliased buffer dead before alias written):
  float* spart = pe;   // (BN,128) == pe exactly; pe dead after k_topk
  float* dpart = xe;   // (BN,128) fits in xe; xe written by k_enc AFTER k_edges
  float* xg    = xe;   // combine output; xe dead after the 3 GHConv gemms
  float* xd    = fh;   // decoder output; fh dead after k_combine

  k_h0   <<<(BN*DIN + 255)/256, 256, 0, stream>>>(X, h0);
  k_pe   <<<BN/2, 256, 0, stream>>>(h0, We1, be1, We2, be2, pe);
  k_binid<<<BN*4/256, 256, 0, stream>>>(pe, R, bid);
  k_place<<<BB*NBINS, 256, 0, stream>>>(bid, order);
  k_topk <<<BB*NBINS*10, 256, 0, stream>>>(pe, order, valk, idxk);
  k_epart<<<BN/2, 256, 0, stream>>>(h0, Wd1, bd1, spart, dpart);
  k_edges<<<BB*EE/4, 256, 0, stream>>>(spart, dpart, order, valk, idxk, Wd1, Wd2, bd2, wgt, dste);
  k_deg  <<<(BN + 255)/256, 256, 0, stream>>>(wgt, order, nrm);
  k_enc  <<<BN/8, 256, 0, stream>>>(h0, Wenc, benc, xe);
  dim3 gg(BN/128, HID/128);
  k_gemm128<0><<<gg, 256, 0, stream>>>(xe, Wh,    nullptr, nullptr, xh);
  k_gemm128<1><<<gg, 256, 0, stream>>>(xe, theta, nullptr, nrm,     fh);
  k_gemm128<2><<<gg, 256, 0, stream>>>(xe, Wt,    bt,      nullptr, gate);
  k_combine<<<BN, 256, 0, stream>>>(fh, xh, gate, wgt, dste, order, nrm, xg);
  k_gemm128<3><<<gg, 256, 0, stream>>>(xg, Wdec,  bdec,    nullptr, xd);
  k_head <<<BN/4, 256, 0, stream>>>(xd, Wout, bout, out);
}

// Round 11
// 1619.476 us; speedup vs baseline: 1.1202x; 1.0152x over previous
//
#include <hip/hip_runtime.h>
#include <cstdint>
#include <cstddef>
#include <math.h>

#define BB    4
#define NN    12800
#define FF    16
#define DIN   23
#define NCLS  8
#define DDIM  128
#define HID   256
#define NBINS 20
#define BS    640
#define KNB   16
#define EE    (NN*KNB)   /* 204800 edges per batch */
#define BN    (BB*NN)    /* 51200 points total */

__device__ __forceinline__ float eluf(float x){ return x > 0.f ? x : expm1f(x); }
__device__ __forceinline__ float seluf(float x){
  const float a = 1.6732632423543772f, s = 1.0507009873554805f;
  return x > 0.f ? s*x : s*a*expm1f(x);
}
__device__ __forceinline__ float sigf(float x){ return 1.f/(1.f+expf(-x)); }

// ---------------- h0 = [one_hot(X[:,:,0],8), X[:,:,1:]] -> (BN,23) ----------
__global__ void k_h0(const float* __restrict__ X, float* __restrict__ h0){
  int id = blockIdx.x*256 + threadIdx.x;
  if (id >= BN*DIN) return;
  int p = id / DIN, f = id % DIN;
  const float* xr = X + (size_t)p*FF;
  float v;
  if (f < NCLS){
    int cls = (int)xr[0];
    v = (f == cls) ? 1.f : 0.f;
  } else {
    v = xr[f - NCLS + 1];
  }
  h0[id] = v;
}

// ------ pe = elu(h0@We1+be1)@We2+be2 -> (BN,128), fp64 internally -----------
// pe feeds the LSH argmax whose flips shift the ENTIRE argsort permutation
// (catastrophic downstream). fp64-then-round makes our pe correctly rounded.
__global__ void k_pe(const float* __restrict__ h0,
                     const float* __restrict__ We1, const float* __restrict__ be1,
                     const float* __restrict__ We2, const float* __restrict__ be2,
                     float* __restrict__ pe){
  __shared__ double hid[2][128];
  int t = threadIdx.x;
  int lp = t >> 7, j = t & 127;
  size_t p = (size_t)blockIdx.x*2 + lp;
  const float* hr = h0 + p*DIN;
  double acc = (double)be1[j];
  #pragma unroll
  for (int k=0;k<DIN;++k) acc += (double)hr[k]*(double)We1[k*DDIM + j];
  hid[lp][j] = acc > 0.0 ? acc : expm1(acc);
  __syncthreads();
  double acc2 = (double)be2[j];
  #pragma unroll 8
  for (int k=0;k<DDIM;++k) acc2 += hid[lp][k]*(double)We2[k*DDIM + j];
  pe[p*DDIM + j] = (float)acc2;
}

// ---------------- LSH bin id: argmax over [pe@R10, -pe@R10] -----------------
// 4 lanes per point; fp64 accumulation (f32 products are exact in f64),
// rounded to f32 before the argmax compare to mirror numpy semantics.
__global__ void k_binid(const float* __restrict__ pe, const float* __restrict__ R,
                        int* __restrict__ bid){
  int tid = blockIdx.x*256 + threadIdx.x;   // grid sized so tid < 4*BN
  int p = tid >> 2, part = tid & 3;
  const float* pr = pe + (size_t)p*DDIM + part*32;
  double m[10];
  #pragma unroll
  for (int j=0;j<10;++j) m[j] = 0.0;
  #pragma unroll 4
  for (int k=0;k<32;++k){
    double v = (double)pr[k];
    const float* rr = R + (size_t)(part*32 + k)*100;  // R (128,100) row-major, cols 0..9
    #pragma unroll
    for (int j=0;j<10;++j) m[j] += v*(double)rr[j];
  }
  #pragma unroll
  for (int j=0;j<10;++j){
    m[j] += __shfl_xor(m[j], 1);
    m[j] += __shfl_xor(m[j], 2);
  }
  if (part == 0){
    float mf[10];
    #pragma unroll
    for (int j=0;j<10;++j) mf[j] = (float)m[j];
    float bv = -1e30f; int bi = 0;
    #pragma unroll
    for (int j=0;j<20;++j){
      float v = (j<10) ? mf[j] : -mf[j-10];
      if (v > bv){ bv = v; bi = j; }   // strict > : first-max = jnp.argmax
    }
    bid[p] = bi;
  }
}

// ---------------- stable counting sort -> order (permutation) ---------------
// one block per (batch, bin); replicates stable argsort of integer keys.
__global__ void k_place(const int* __restrict__ binid, int* __restrict__ order){
  int b = blockIdx.x / NBINS, mybin = blockIdx.x % NBINS;
  const int* bid = binid + (size_t)b*NN;
  int t = threadIdx.x;
  __shared__ int wsum[4];
  __shared__ int wtot[4];
  __shared__ int sOff;
  // offset = #points with smaller bin id
  int c = 0;
  for (int i = t; i < NN; i += 256) c += (bid[i] < mybin) ? 1 : 0;
  #pragma unroll
  for (int o=32;o;o>>=1) c += __shfl_xor(c, o);
  if ((t & 63) == 0) wsum[t >> 6] = c;
  __syncthreads();
  if (t == 0) sOff = wsum[0]+wsum[1]+wsum[2]+wsum[3];
  __syncthreads();
  int base = sOff;
  int lane = t & 63, w = t >> 6;
  for (int ch = 0; ch < NN; ch += 256){
    int i = ch + t;
    bool flag = (i < NN) && (bid[i] == mybin);
    unsigned long long bal = __ballot(flag);
    int pre = __popcll(bal & ((1ull << lane) - 1ull));
    if (lane == 0) wtot[w] = __popcll(bal);
    __syncthreads();
    int woff = 0;
    #pragma unroll
    for (int ww=0; ww<4; ++ww) if (ww < w) woff += wtot[ww];
    if (flag) order[(size_t)b*NN + base + woff + pre] = i;
    base += wtot[0]+wtot[1]+wtot[2]+wtot[3];
    __syncthreads();
  }
}

// ---------------- per-bin dense sim + top-16, 4x4 register blocking ---------
// block = (batch, bin, row-tile of 64). Rows staged ONCE full-K in rowF;
// cols staged per (ct,kh) in colT. Compute: thread (tm=t&15, tn=t>>4) owns
// 4 rows x 4 cols: per kk 2x ds_read_b128 (4-way broadcast, conflict-free)
// for 16 FMAs -- 2.5x fewer LDS instructions than the row-owner layout.
// S^T (aliasing colT) carries the sigmoid values to the per-row selection
// threads (rsel=t&63 owns row, qsel=t>>6 scans 16 cols). Accumulation order
// per (row,col) is k=0..127 ascending -> bit-identical to prior rounds.
#define TPAD 68
__global__ void __launch_bounds__(256)
k_topk(const float* __restrict__ pe, const int* __restrict__ order,
       float* __restrict__ valk, int* __restrict__ idxk){
  __shared__ float rowF[128][TPAD];  // [k][row], full K resident
  __shared__ float colT[64][TPAD];   // [k_local][col]; reused as S^T [col][row]
  __shared__ int ordRow[64];
  __shared__ int ordCol[64];
  int blk = blockIdx.x;
  int b   = blk / (NBINS*10);
  int rem = blk % (NBINS*10);
  int bin = rem / 10, rt = rem % 10;
  int r0 = rt*64;
  int t = threadIdx.x;
  int tm = t & 15, tn = t >> 4;     // compute mapping: rows 4tm.., cols 4tn..
  int rsel = t & 63, qsel = t >> 6; // selection mapping: row rsel, col-quarter qsel
  const float* peb = pe + (size_t)b*NN*DDIM;
  const int* ob = order + (size_t)b*NN + (size_t)bin*BS;
  if (t < 64) ordRow[t] = ob[r0 + t];
  __syncthreads();                   // ordRow visible for rowF staging
  // stage the 64-row tile, full K (coalesced global; one-time LDS writes)
  for (int l=t; l<8192; l+=256){
    int rr = l >> 7, kk = l & 127;
    rowF[kk][rr] = peb[(size_t)ordRow[rr]*DDIM + kk];
  }

  float tv[16]; int ti[16];
  #pragma unroll
  for (int j=0;j<16;++j){ tv[j] = -1e30f; ti[j] = 1<<20; }
  float wv = -1e30f; int wi = 1<<20; int wpos = 0;

  float (*S_T)[TPAD] = colT;         // S^T[col][row] aliases colT

  for (int ct = 0; ct < 10; ++ct){
    if (t < 64) ordCol[t] = ob[ct*64 + t];
    float acc[4][4];
    #pragma unroll
    for (int i=0;i<4;++i){
      #pragma unroll
      for (int j=0;j<4;++j) acc[i][j] = 0.f;
    }
    #pragma unroll
    for (int kh = 0; kh < 2; ++kh){
      __syncthreads();               // prev reads of colT/S_T done; ordCol visible
      for (int l=t; l<4096; l+=256){
        int cc = l >> 6, kk = l & 63;
        colT[kk][cc] = peb[(size_t)ordCol[cc]*DDIM + kh*64 + kk];
      }
      __syncthreads();
      #pragma unroll 4
      for (int kk=0; kk<64; ++kk){
        float4 a = *(const float4*)&rowF[kh*64 + kk][4*tm];
        float4 w = *(const float4*)&colT[kk][4*tn];
        acc[0][0]+=a.x*w.x; acc[0][1]+=a.x*w.y; acc[0][2]+=a.x*w.z; acc[0][3]+=a.x*w.w;
        acc[1][0]+=a.y*w.x; acc[1][1]+=a.y*w.y; acc[1][2]+=a.y*w.z; acc[1][3]+=a.y*w.w;
        acc[2][0]+=a.z*w.x; acc[2][1]+=a.z*w.y; acc[2][2]+=a.z*w.z; acc[2][3]+=a.z*w.w;
        acc[3][0]+=a.w*w.x; acc[3][1]+=a.w*w.y; acc[3][2]+=a.w*w.z; acc[3][3]+=a.w*w.w;
      }
    }
    __syncthreads();                 // compute reads of colT done; safe to write S_T
    #pragma unroll
    for (int i=0;i<4;++i){
      #pragma unroll
      for (int j=0;j<4;++j)
        S_T[4*tn+j][4*tm+i] = sigf(acc[i][j]);
    }
    __syncthreads();
    // selection: thread (rsel,qsel) streams its 16 candidates of row rsel
    #pragma unroll
    for (int j=0;j<16;++j){
      float v = S_T[qsel*16 + j][rsel];
      int gc = ct*64 + qsel*16 + j;
      bool better = (v > wv) || (v == wv && gc < wi);
      if (better){
        #pragma unroll
        for (int u=0;u<16;++u){ if (u == wpos){ tv[u] = v; ti[u] = gc; } }
        wv = tv[0]; wi = ti[0]; wpos = 0;
        #pragma unroll
        for (int u=1;u<16;++u){
          bool worse = (tv[u] < wv) || (tv[u] == wv && ti[u] > wi);
          if (worse){ wv = tv[u]; wi = ti[u]; wpos = u; }
        }
      }
    }
  }
  // ---- merge the 4 per-quarter lists per row (reuse rowF LDS) ----
  __syncthreads();
  float* mv = (float*)&rowF[0][0];   // [64][49] values
  int*   mi = (int*)  &rowF[64][0];  // [64][49] indices
  const int MS = 49;                 // odd stride -> conflict-free
  if (qsel > 0){
    #pragma unroll
    for (int j=0;j<16;++j){
      mv[rsel*MS + (qsel-1)*16 + j] = tv[j];
      mi[rsel*MS + (qsel-1)*16 + j] = ti[j];
    }
  }
  __syncthreads();
  if (qsel == 0){
    for (int j=0;j<48;++j){
      float v = mv[rsel*MS + j];
      int gc  = mi[rsel*MS + j];
      bool better = (v > wv) || (v == wv && gc < wi);
      if (better){
        #pragma unroll
        for (int u=0;u<16;++u){ if (u == wpos){ tv[u] = v; ti[u] = gc; } }
        wv = tv[0]; wi = ti[0]; wpos = 0;
        #pragma unroll
        for (int u=1;u<16;++u){
          bool worse = (tv[u] < wv) || (tv[u] == wv && ti[u] > wi);
          if (worse){ wv = tv[u]; wi = ti[u]; wpos = u; }
        }
      }
    }
    size_t base = (((size_t)(b*NBINS + bin))*BS + r0 + rsel)*KNB;
    #pragma unroll
    for (int j=0;j<16;++j){ valk[base + j] = tv[j]; idxk[base + j] = ti[j]; }
  }
}

// -------- per-node edge-FFN partials: spart = bd1 + h0@Wd1[0:23],
//          dpart = h0@Wd1[23:46]  (each (BN,128)) -----------------------------
__global__ void k_epart(const float* __restrict__ h0,
                        const float* __restrict__ Wd1, const float* __restrict__ bd1,
                        float* __restrict__ spart, float* __restrict__ dpart){
  int t = threadIdx.x;
  int lp = t >> 7, j = t & 127;
  size_t p = (size_t)blockIdx.x*2 + lp;
  const float* hr = h0 + p*DIN;
  float sa = bd1[j];
  float da = 0.f;
  #pragma unroll
  for (int k=0;k<DIN;++k){
    float x = hr[k];
    sa += x*Wd1[k*128 + j];
    da += x*Wd1[(DIN+k)*128 + j];
  }
  spart[p*128 + j] = sa;
  dpart[p*128 + j] = da;
}

// ---------------- edge FFN (decomposed): one wave per edge ------------------
__global__ void k_edges(const float* __restrict__ spart, const float* __restrict__ dpart,
                        const int* __restrict__ order,
                        const float* __restrict__ valk, const int* __restrict__ idxk,
                        const float* __restrict__ Wd1, const float* __restrict__ Wd2,
                        const float* __restrict__ bd2,
                        float* __restrict__ wgt, int* __restrict__ dste){
  int lane = threadIdx.x & 63;
  size_t e = (size_t)blockIdx.x*4 + (threadIdx.x >> 6);
  int b  = (int)(e / EE);
  int eb = (int)(e % EE);
  int bin = eb / (BS*KNB);
  int rem = eb % (BS*KNB);
  int i  = rem / KNB;
  int kk = rem % KNB;
  const int* ob = order + (size_t)b*NN + (size_t)bin*BS;
  int src = ob[i];
  size_t tkb = ((size_t)(b*NBINS + bin)*BS + i)*KNB + kk;
  int ip = idxk[tkb];
  int dst = ob[ip];
  float dv = valk[tkb];
  size_t gs = ((size_t)b*NN + src)*128;
  size_t gd = ((size_t)b*NN + dst)*128;
  float a1 = spart[gs + lane]      + dpart[gd + lane]      + dv*Wd1[46*128 + lane];
  float a2 = spart[gs + 64 + lane] + dpart[gd + 64 + lane] + dv*Wd1[46*128 + 64 + lane];
  float ptl = eluf(a1)*Wd2[lane] + eluf(a2)*Wd2[lane + 64];
  #pragma unroll
  for (int o=32;o;o>>=1) ptl += __shfl_xor(ptl, o);
  if (lane == 0){
    wgt[e]  = sigf(ptl + bd2[0]);
    dste[e] = dst;
  }
}

// ---------------- degree -> norm (per node) ---------------------------------
__global__ void k_deg(const float* __restrict__ wgt, const int* __restrict__ order,
                      float* __restrict__ nrm){
  int id = blockIdx.x*256 + threadIdx.x;
  if (id >= BN) return;
  int b = id / NN;
  int p = id % NN;
  const float* w = wgt + (size_t)b*EE + (size_t)p*KNB;
  float s = 0.f;
  #pragma unroll
  for (int k=0;k<KNB;++k) s += fabsf(w[k]);
  int node = order[id];
  nrm[(size_t)b*NN + node] = 1.f/sqrtf(s + 1e-6f);
}

// ---------------- encoder: selu(h0@Wenc+benc), 8 points / block -------------
__global__ void k_enc(const float* __restrict__ h0, const float* __restrict__ Wenc,
                      const float* __restrict__ benc, float* __restrict__ xe){
  __shared__ float hs[8][DIN+1];
  size_t p0 = (size_t)blockIdx.x*8;
  int t = threadIdx.x;
  if (t < 8*DIN){
    int pp = t / DIN, ff = t - pp*DIN;
    hs[pp][ff] = h0[(p0+pp)*DIN + ff];
  }
  float wreg[DIN];
  #pragma unroll
  for (int k=0;k<DIN;++k) wreg[k] = Wenc[k*HID + t];
  float bb = benc[t];
  __syncthreads();
  #pragma unroll
  for (int pp=0;pp<8;++pp){
    float acc = bb;
    #pragma unroll
    for (int k=0;k<DIN;++k) acc += hs[pp][k]*wreg[k];
    xe[(p0+pp)*HID + t] = seluf(acc);
  }
}

// ------- 128x128-tile GEMM: (BN x 256) @ (256 x 256), 8x8 per thread --------
// MODE 0: C=A@W ; 1: C=(A@W)*rs[row] ; 2: sigmoid(A@W+b) ; 3: selu(A@W+b)
template<int MODE>
__global__ void __launch_bounds__(256)
k_gemm128(const float* __restrict__ A, const float* __restrict__ W,
          const float* __restrict__ bias, const float* __restrict__ rs,
          float* __restrict__ C){
  __shared__ float As[16][132];   // [k][m] transposed A tile
  __shared__ float Ws[16][132];   // [k][n]
  int t = threadIdx.x;
  int m0 = blockIdx.x*128, n0 = blockIdx.y*128;
  int tx = t & 15, ty = t >> 4;
  float acc[8][8];
  #pragma unroll
  for (int i=0;i<8;++i){
    #pragma unroll
    for (int j=0;j<8;++j) acc[i][j] = 0.f;
  }
  for (int kt=0; kt<16; ++kt){
    int k0 = kt*16;
    __syncthreads();
    #pragma unroll
    for (int l=0;l<8;++l){
      int idx = t + l*256;
      int m = idx >> 4, kk = idx & 15;
      As[kk][m] = A[((size_t)(m0+m))*HID + k0 + kk];
    }
    #pragma unroll
    for (int l=0;l<8;++l){
      int idx = t + l*256;
      int kk = idx >> 7, nn = idx & 127;
      Ws[kk][nn] = W[((size_t)(k0+kk))*HID + n0 + nn];
    }
    __syncthreads();
    #pragma unroll
    for (int kk=0;kk<16;++kk){
      float4 a0 = *(const float4*)&As[kk][4*ty];
      float4 a1 = *(const float4*)&As[kk][64 + 4*ty];
      float4 w0 = *(const float4*)&Ws[kk][4*tx];
      float4 w1 = *(const float4*)&Ws[kk][64 + 4*tx];
      float av[8], wv[8];
      av[0]=a0.x; av[1]=a0.y; av[2]=a0.z; av[3]=a0.w;
      av[4]=a1.x; av[5]=a1.y; av[6]=a1.z; av[7]=a1.w;
      wv[0]=w0.x; wv[1]=w0.y; wv[2]=w0.z; wv[3]=w0.w;
      wv[4]=w1.x; wv[5]=w1.y; wv[6]=w1.z; wv[7]=w1.w;
      #pragma unroll
      for (int i=0;i<8;++i){
        #pragma unroll
        for (int j=0;j<8;++j) acc[i][j] += av[i]*wv[j];
      }
    }
  }
  float b0[8];
  if (MODE == 2 || MODE == 3){
    #pragma unroll
    for (int j=0;j<8;++j) b0[j] = bias[n0 + (j<4 ? 4*tx+j : 60+4*tx+j)];
  }
  #pragma unroll
  for (int i=0;i<8;++i){
    int row = m0 + (i<4 ? 4*ty+i : 60+4*ty+i);
    float sc = (MODE == 1) ? rs[row] : 1.f;
    float v[8];
    #pragma unroll
    for (int j=0;j<8;++j){
      float x = acc[i][j];
      if (MODE == 2 || MODE == 3) x += b0[j];
      if (MODE == 1) x *= sc;
      if (MODE == 2) x = sigf(x);
      if (MODE == 3) x = seluf(x);
      v[j] = x;
    }
    float4 r0; r0.x=v[0]; r0.y=v[1]; r0.z=v[2]; r0.w=v[3];
    float4 r1; r1.x=v[4]; r1.y=v[5]; r1.z=v[6]; r1.w=v[7];
    *(float4*)&C[(size_t)row*HID + n0 + 4*tx]      = r0;
    *(float4*)&C[(size_t)row*HID + n0 + 64 + 4*tx] = r1;
  }
}

// ---------------- GHConv combine --------------------------------------------
__global__ void k_combine(const float* __restrict__ fh, const float* __restrict__ xh,
                          const float* __restrict__ gate, const float* __restrict__ wgt,
                          const int* __restrict__ dste, const int* __restrict__ order,
                          const float* __restrict__ nrm, float* __restrict__ xg){
  __shared__ float ew[KNB];
  __shared__ int   ed[KNB];
  int blk = blockIdx.x;
  int b = blk / NN, p = blk % NN;
  int t = threadIdx.x;
  if (t < KNB){
    size_t e = (size_t)b*EE + (size_t)p*KNB + t;
    ew[t] = wgt[e];
    ed[t] = dste[e];
  }
  __syncthreads();
  int src = order[(size_t)b*NN + p];
  float nr = nrm[(size_t)b*NN + src];
  size_t base = (size_t)b*NN*HID;
  float acc = 0.f;
  #pragma unroll
  for (int k=0;k<KNB;++k) acc += ew[k]*fh[base + (size_t)ed[k]*HID + t];
  acc *= nr;
  size_t o = base + (size_t)src*HID + t;
  float g = gate[o];
  xg[o] = seluf(g*acc + (1.f - g)*xh[o]);
}

// ---------------- output head: one wave per point ---------------------------
__global__ void k_head(const float* __restrict__ xd, const float* __restrict__ Wout,
                       const float* __restrict__ bout, float* __restrict__ out){
  int lane = threadIdx.x & 63;
  size_t p = (size_t)blockIdx.x*4 + (threadIdx.x >> 6);
  float4 x = *(const float4*)&xd[p*HID + lane*4];
  float a0 = 0.f, a1 = 0.f, a2 = 0.f;
  const float* wr = Wout + lane*4*3;
  a0 += x.x*wr[0]; a1 += x.x*wr[1]; a2 += x.x*wr[2];
  a0 += x.y*wr[3]; a1 += x.y*wr[4]; a2 += x.y*wr[5];
  a0 += x.z*wr[6]; a1 += x.z*wr[7]; a2 += x.z*wr[8];
  a0 += x.w*wr[9]; a1 += x.w*wr[10]; a2 += x.w*wr[11];
  #pragma unroll
  for (int o=32;o;o>>=1){
    a0 += __shfl_xor(a0, o);
    a1 += __shfl_xor(a1, o);
    a2 += __shfl_xor(a2, o);
  }
  if (lane == 0){
    out[p*3 + 0] = a0 + bout[0];
    out[p*3 + 1] = a1 + bout[1];
    out[p*3 + 2] = a2 + bout[2];
  }
}

// ---------------------------------------------------------------------------
extern "C" void kernel_launch(void* const* d_in, const int* in_sizes, int n_in,
                              void* d_out, int out_size, void* d_ws, size_t ws_size,
                              hipStream_t stream){
  (void)in_sizes; (void)n_in; (void)out_size; (void)ws_size;
  const float* X    = (const float*)d_in[0];
  const float* We1  = (const float*)d_in[1];
  const float* be1  = (const float*)d_in[2];
  const float* We2  = (const float*)d_in[3];
  const float* be2  = (const float*)d_in[4];
  const float* Wd1  = (const float*)d_in[5];
  const float* bd1  = (const float*)d_in[6];
  const float* Wd2  = (const float*)d_in[7];
  const float* bd2  = (const float*)d_in[8];
  const float* R    = (const float*)d_in[9];
  const float* Wenc = (const float*)d_in[10];
  const float* benc = (const float*)d_in[11];
  const float* Wt   = (const float*)d_in[12];
  const float* bt   = (const float*)d_in[13];
  const float* Wh   = (const float*)d_in[14];
  const float* theta= (const float*)d_in[15];
  const float* Wdec = (const float*)d_in[16];
  const float* bdec = (const float*)d_in[17];
  const float* Wout = (const float*)d_in[18];
  const float* bout = (const float*)d_in[19];
  float* out = (float*)d_out;

  char* ws = (char*)d_ws; size_t off = 0;
  auto alloc = [&](size_t bytes)->void*{
    void* p = ws + off; off = (off + bytes + 255) & ~(size_t)255; return p;
  };
  float* h0   = (float*)alloc((size_t)BN*DIN*4);
  float* pe   = (float*)alloc((size_t)BN*DDIM*4);
  int*   bid  = (int*)  alloc((size_t)BN*4);
  int*   order= (int*)  alloc((size_t)BN*4);
  float* valk = (float*)alloc((size_t)BB*NBINS*BS*KNB*4);
  int*   idxk = (int*)  alloc((size_t)BB*NBINS*BS*KNB*4);
  float* wgt  = (float*)alloc((size_t)BB*EE*4);
  int*   dste = (int*)  alloc((size_t)BB*EE*4);
  float* nrm  = (float*)alloc((size_t)BN*4);
  float* xe   = (float*)alloc((size_t)BN*HID*4);
  float* fh   = (float*)alloc((size_t)BN*HID*4);
  float* xh   = (float*)alloc((size_t)BN*HID*4);
  float* gate = (float*)alloc((size_t)BN*HID*4);
  // aliases (stream-ordered; aliased buffer dead before alias written):
  float* spart = pe;   // (BN,128) == pe exactly; pe dead after k_topk
  float* dpart = xe;   // (BN,128) fits in xe; xe written by k_enc AFTER k_edges
  float* xg    = xe;   // combine output; xe dead after the 3 GHConv gemms
  float* xd    = fh;   // decoder output; fh dead after k_combine

  k_h0   <<<(BN*DIN + 255)/256, 256, 0, stream>>>(X, h0);
  k_pe   <<<BN/2, 256, 0, stream>>>(h0, We1, be1, We2, be2, pe);
  k_binid<<<BN*4/256, 256, 0, stream>>>(pe, R, bid);
  k_place<<<BB*NBINS, 256, 0, stream>>>(bid, order);
  k_topk <<<BB*NBINS*10, 256, 0, stream>>>(pe, order, valk, idxk);
  k_epart<<<BN/2, 256, 0, stream>>>(h0, Wd1, bd1, spart, dpart);
  k_edges<<<BB*EE/4, 256, 0, stream>>>(spart, dpart, order, valk, idxk, Wd1, Wd2, bd2, wgt, dste);
  k_deg  <<<(BN + 255)/256, 256, 0, stream>>>(wgt, order, nrm);
  k_enc  <<<BN/8, 256, 0, stream>>>(h0, Wenc, benc, xe);
  dim3 gg(BN/128, HID/128);
  k_gemm128<0><<<gg, 256, 0, stream>>>(xe, Wh,    nullptr, nullptr, xh);
  k_gemm128<1><<<gg, 256, 0, stream>>>(xe, theta, nullptr, nrm,     fh);
  k_gemm128<2><<<gg, 256, 0, stream>>>(xe, Wt,    bt,      nullptr, gate);
  k_combine<<<BN, 256, 0, stream>>>(fh, xh, gate, wgt, dste, order, nrm, xg);
  k_gemm128<3><<<gg, 256, 0, stream>>>(xg, Wdec,  bdec,    nullptr, xd);
  k_head <<<BN/4, 256, 0, stream>>>(xd, Wout, bout, out);
}